// Round 4
// baseline (394.897 us; speedup 1.0000x reference)
//
#include <hip/hip_runtime.h>
#include <math.h>

#define BB 4
#define SS 2048
#define DD 1024
#define MM (BB*SS)                   // 8192
#define SD ((size_t)SS*DD)
#define MD ((size_t)MM*DD)           // 8,388,608
#define PPB ((size_t)2162688)        // packed P elems per batch

// ws (bf16 elems): Q@0 | K@MD | VT@2MD | P@3MD (4*PPB) | WT@3MD+4PPB (6*DD*DD) | zpad(16)
#define WT_OFF (3*MD + 4*PPB)
#define ZP_OFF (WT_OFF + 6*(size_t)DD*DD)
#define REQ_WS ((ZP_OFF + 16) * 2)

constexpr float LN_EPS = 1e-6f;

typedef __attribute__((ext_vector_type(8))) __bf16 bf16x8;
typedef __attribute__((ext_vector_type(4))) float f32x4;

__device__ __forceinline__ unsigned short f2bfbits(float f){
    unsigned u = __float_as_uint(f);
    u += 0x7FFFu + ((u >> 16) & 1u);   // RNE
    return (unsigned short)(u >> 16);
}
__device__ __forceinline__ int rowWidth(int s){ return ((s >> 6) + 1) << 6; }
__device__ __forceinline__ size_t rowOff(int s){
    int g = s >> 6;
    return (size_t)4096 * (size_t)((g * (g + 1)) >> 1) + (size_t)(s & 63) * (size_t)((g + 1) << 6);
}
// async global->LDS, 16B per lane; LDS dest = wave-uniform base + lane*16
__device__ __forceinline__ void gl_lds(const unsigned short* g, unsigned short* l){
    __builtin_amdgcn_global_load_lds(
        (const __attribute__((address_space(1))) unsigned int*)g,
        (__attribute__((address_space(3))) unsigned int*)l, 16, 0, 0);
}

// XCD-aware bijective block swizzle (T1): each of the 8 XCDs gets a
// contiguous chunk of the linearized grid -> neighbor tiles share L2.
// Valid because every MFMA launch here has (gx*gy*gz) % 8 == 0.
__device__ __forceinline__ int3 xcd_swz(){
    const int gx = gridDim.x, gy = gridDim.y, gz = gridDim.z;
    const int n = gx * gy * gz;
    int lin = blockIdx.x + gx * (blockIdx.y + gy * blockIdx.z);
    const int cpx = n >> 3;                 // n % 8 == 0 for all launches
    lin = (lin & 7) * cpx + (lin >> 3);     // bijection: XCD (lin&7) owns chunk
    int3 r;
    r.x = lin % gx; lin /= gx;
    r.y = lin % gy;
    r.z = lin / gy;
    return r;
}

__global__ __launch_bounds__(256)
void sentinel_kernel(float* __restrict__ out, const float val){
    out[(size_t)blockIdx.x * 256 + threadIdx.x] = val;
}

// ---------- weight transpose W[K][N] f32 -> WT[N][K] bf16 ; also zeroes zpad ----------
struct WPack { const float* w[6]; unsigned short* o[6]; unsigned short* zp; };
__global__ __launch_bounds__(256)
void wtrans(WPack wp)
{
    __shared__ float Ts[64][65];
    const float* W = wp.w[blockIdx.z];
    unsigned short* WT = wp.o[blockIdx.z];
    const int r0 = blockIdx.y*64, c0 = blockIdx.x*64;
    const int tid = threadIdx.x;
    if (blockIdx.x == 0 && blockIdx.y == 0 && blockIdx.z == 0 && tid < 16) wp.zp[tid] = 0;
    #pragma unroll
    for (int i = 0; i < 16; ++i){
        int lin = tid + i*256;
        int r = lin >> 6, c = lin & 63;
        Ts[r][c] = W[(size_t)(r0+r)*DD + c0+c];
    }
    __syncthreads();
    #pragma unroll
    for (int i = 0; i < 16; ++i){
        int lin = tid + i*256;
        int r = lin >> 6, c = lin & 63;
        WT[(size_t)(c0+r)*DD + r0+c] = f2bfbits(Ts[c][r]);
    }
}

// ---------- LayerNorm: fp32 in -> bf16 out ----------
__global__ __launch_bounds__(256)
void ln_f32(const float* __restrict__ x, const float* __restrict__ gamma,
            const float* __restrict__ beta, unsigned short* __restrict__ out)
{
    __shared__ float red[4];
    const int row = blockIdx.x;
    const int tid = threadIdx.x;
    float4 xv = ((const float4*)(x + (size_t)row*DD))[tid];
    float v[4] = {xv.x, xv.y, xv.z, xv.w};
    float s = v[0]+v[1]+v[2]+v[3];
    #pragma unroll
    for (int off = 32; off > 0; off >>= 1) s += __shfl_down(s, off, 64);
    if ((tid & 63) == 0) red[tid >> 6] = s;
    __syncthreads();
    const float mean = (red[0]+red[1]+red[2]+red[3]) * (1.0f/DD);
    __syncthreads();
    float q = 0.f;
    #pragma unroll
    for (int i = 0; i < 4; ++i){ float d = v[i]-mean; q += d*d; }
    #pragma unroll
    for (int off = 32; off > 0; off >>= 1) q += __shfl_down(q, off, 64);
    if ((tid & 63) == 0) red[tid >> 6] = q;
    __syncthreads();
    const float var = (red[0]+red[1]+red[2]+red[3]) * (1.0f/(DD-1));
    const float inv = 1.0f/(sqrtf(var) + LN_EPS);
    float4 g4 = ((const float4*)gamma)[tid];
    float4 b4 = ((const float4*)beta)[tid];
    ushort4 o;
    o.x = f2bfbits(g4.x*(v[0]-mean)*inv + b4.x);
    o.y = f2bfbits(g4.y*(v[1]-mean)*inv + b4.y);
    o.z = f2bfbits(g4.z*(v[2]-mean)*inv + b4.z);
    o.w = f2bfbits(g4.w*(v[3]-mean)*inv + b4.w);
    ((ushort4*)(out + (size_t)row*DD))[tid] = o;
}

// =========== 8-wave pipelined GEMM main loop, STATIC double-pair buffers ===========
// Fills acc[4][4] for a C[256,128] tile. BK=64, 512 thr (8 waves 4Mx2N).
// Two STATIC buffer pairs (A_0/B_0, A_1/B_1 as distinct __shared__ arrays, no
// pointer rotation) so the waitcnt pass can disambiguate in-flight LDS-DMA
// (global_load_lds) from ds_reads of the other pair -> no spurious vmcnt(0).
// Per iteration (2 K-tiles, 4 phases): stage-issues at phase heads (after the
// barrier proving the target pair's readers drained), vmcnt(0) waits 2 phases
// after issue, lgkmcnt(0)+sched_barrier(0)+setprio around each MFMA cluster.
// NT must be even and >= 2 (all call sites: 16 or 4*(y+1)).
template<bool PACKED_A>
__device__ __forceinline__ void gemm_loop8(
    const unsigned short* const ga[4], const unsigned short* const gb[2],
    const int* pw, const unsigned short* zpad, const int NT,
    f32x4 acc[4][4], const int wave, const int lane,
    unsigned short (&A_0)[16384], unsigned short (&B_0)[8192],
    unsigned short (&A_1)[16384], unsigned short (&B_1)[8192])
{
    const int quad = lane >> 4, l15 = lane & 15;
    const int wr = (wave >> 1) * 64;      // wave row offset in 256
    const int wc = (wave & 1) * 64;       // wave col offset in 128

    auto stage = [&](unsigned short (&Ab)[16384], unsigned short (&Bb)[8192], int koff){
        #pragma unroll
        for (int c = 0; c < 4; ++c){
            const unsigned short* gp = ga[c] + koff;
            if constexpr (PACKED_A) { if (koff >= pw[c]) gp = zpad; }
            gl_lds(gp, &Ab[(wave*4+c)*512]);
        }
        #pragma unroll
        for (int c = 0; c < 2; ++c) gl_lds(gb[c] + koff, &Bb[(wave*2+c)*512]);
    };
    auto phase = [&](unsigned short (&Ab)[16384], unsigned short (&Bb)[8192],
                     const int kk, const bool wait_vm){
        bf16x8 af[4], bfr[4];
        #pragma unroll
        for (int u = 0; u < 4; ++u){
            const int ra = wr + u*16 + l15, rb = wc + u*16 + l15, gi = kk*4 + quad;
            af[u]  = *(const bf16x8*)&Ab[ra*64 + (((gi + ra) & 7) << 3)];
            bfr[u] = *(const bf16x8*)&Bb[rb*64 + (((gi + rb) & 7) << 3)];
        }
        __builtin_amdgcn_s_barrier();
        asm volatile("s_waitcnt lgkmcnt(0)" ::: "memory");
        __builtin_amdgcn_sched_barrier(0);
        __builtin_amdgcn_s_setprio(1);
        #pragma unroll
        for (int i = 0; i < 4; ++i)
            #pragma unroll
            for (int j = 0; j < 4; ++j)
                acc[i][j] = __builtin_amdgcn_mfma_f32_16x16x32_bf16(af[i], bfr[j], acc[i][j], 0, 0, 0);
        __builtin_amdgcn_s_setprio(0);
        if (wait_vm)
            asm volatile("s_waitcnt vmcnt(0)" ::: "memory");   // set issued 2 phases ago; only set in flight
        __builtin_amdgcn_s_barrier();
    };

    // prologue: stage tile0 -> pair0, tile1 -> pair1; wait pair0 only (counted)
    stage(A_0, B_0, 0);
    stage(A_1, B_1, 64);
    asm volatile("s_waitcnt vmcnt(6)" ::: "memory");
    __builtin_amdgcn_s_barrier();

    const int half = NT >> 1;
    for (int i = 0; i < half; ++i){
        // pair1 refill (tile 2i+1) — readers of old pair1 drained before prev
        // phase-D closing barrier; iter 0's tile1 came from the prologue.
        if (i > 0) stage(A_1, B_1, (2*i + 1) << 6);
        phase(A_0, B_0, 0, false);          // tile 2i, kk=0
        phase(A_0, B_0, 1, true);           // tile 2i, kk=1 ; wait pair1 landed
        // pair0 refill (tile 2i+2; clamped on last iter -> benign dup write)
        int kc = 2*i + 2; if (kc > NT - 1) kc = NT - 1;
        stage(A_0, B_0, kc << 6);
        phase(A_1, B_1, 0, false);          // tile 2i+1, kk=0
        phase(A_1, B_1, 1, true);           // tile 2i+1, kk=1 ; wait pair0 landed
    }
    asm volatile("s_waitcnt vmcnt(0)" ::: "memory");   // drain dummy tail stage
}

// A-chunk pointers for 256 rows (4 chunks/wave), B-chunk pointers for 128 rows (2 chunks/wave)
__device__ __forceinline__ void mk_ga(const unsigned short* base, size_t ld, int r0,
                                      int wave, int lane, const unsigned short* ga[4]){
    #pragma unroll
    for (int c = 0; c < 4; ++c){
        const int mr = (wave*4 + c)*8 + (lane >> 3);
        const int gk = ((lane & 7) - mr) & 7;
        ga[c] = base + (size_t)(r0 + mr)*ld + gk*8;
    }
}
__device__ __forceinline__ void mk_gb(const unsigned short* base, size_t ld, int r0,
                                      int wave, int lane, const unsigned short* gb[2]){
    #pragma unroll
    for (int c = 0; c < 2; ++c){
        const int mr = (wave*2 + c)*8 + (lane >> 3);
        const int gk = ((lane & 7) - mr) & 7;
        gb[c] = base + (size_t)(r0 + mr)*ld + gk*8;
    }
}

#define DECL_PAIRS \
    __shared__ unsigned short A_0[16384]; \
    __shared__ unsigned short B_0[8192];  \
    __shared__ unsigned short A_1[16384]; \
    __shared__ unsigned short B_1[8192];

// generic single GEMM (256x128 tiles, 512 threads): C = A[M,K] * B[N,K]^T
template<bool RELU, bool RES, bool OUTF, bool BIAS_M>
__global__ __launch_bounds__(512)
void gemm_mfma(const unsigned short* __restrict__ A, const unsigned short* __restrict__ B,
               const float* __restrict__ bias, const float* __restrict__ resF,
               unsigned short* __restrict__ outB, float* __restrict__ outF,
               const int N, const int K, const int lda, const int ldb)
{
    DECL_PAIRS
    const int3 b = xcd_swz();
    const int m0 = b.y*256, n0 = b.x*128;
    const int tid = threadIdx.x, lane = tid & 63, wave = tid >> 6;
    const unsigned short* ga[4]; const unsigned short* gb[2];
    mk_ga(A, lda, m0, wave, lane, ga);
    mk_gb(B, ldb, n0, wave, lane, gb);
    f32x4 acc[4][4] = {};
    gemm_loop8<false>(ga, gb, nullptr, nullptr, K >> 6, acc, wave, lane, A_0, B_0, A_1, B_1);

    const int quad = lane >> 4, l15 = lane & 15;
    const int wr = (wave >> 1) * 64, wc = (wave & 1) * 64;
    #pragma unroll
    for (int i = 0; i < 4; ++i){
        #pragma unroll
        for (int r = 0; r < 4; ++r){
            const int m = m0 + wr + i*16 + quad*4 + r;
            const float bm = BIAS_M ? bias[m] : 0.f;
            #pragma unroll
            for (int j = 0; j < 4; ++j){
                const int n = n0 + wc + j*16 + l15;
                float v = acc[i][j][r] + (BIAS_M ? bm : bias[n]);
                if constexpr (RELU) v = fmaxf(v, 0.f);
                if constexpr (RES) v += resF[(size_t)m*N + n];
                if constexpr (OUTF) outF[(size_t)m*N + n] = v;
                else outB[(size_t)m*N + n] = f2bfbits(v);
            }
        }
    }
}

// merged Q+K projection (z=0 -> Q, z=1 -> K)
__global__ __launch_bounds__(512)
void gemm_qk(const unsigned short* __restrict__ LN,
             const unsigned short* __restrict__ WqT, const unsigned short* __restrict__ WkT,
             const float* __restrict__ bq, const float* __restrict__ bk,
             unsigned short* __restrict__ Qw, unsigned short* __restrict__ Kw)
{
    DECL_PAIRS
    const int3 b = xcd_swz();
    const bool isK = (b.z != 0);
    const unsigned short* Bw = isK ? WkT : WqT;
    const float* bias = isK ? bk : bq;
    unsigned short* out = isK ? Kw : Qw;
    const int m0 = b.y*256, n0 = b.x*128;
    const int tid = threadIdx.x, lane = tid & 63, wave = tid >> 6;
    const unsigned short* ga[4]; const unsigned short* gb[2];
    mk_ga(LN, DD, m0, wave, lane, ga);
    mk_gb(Bw, DD, n0, wave, lane, gb);
    f32x4 acc[4][4] = {};
    gemm_loop8<false>(ga, gb, nullptr, nullptr, DD >> 6, acc, wave, lane, A_0, B_0, A_1, B_1);

    const int quad = lane >> 4, l15 = lane & 15;
    const int wr = (wave >> 1) * 64, wc = (wave & 1) * 64;
    #pragma unroll
    for (int i = 0; i < 4; ++i){
        #pragma unroll
        for (int r = 0; r < 4; ++r){
            const int m = m0 + wr + i*16 + quad*4 + r;
            #pragma unroll
            for (int j = 0; j < 4; ++j){
                const int n = n0 + wc + j*16 + l15;
                out[(size_t)m*DD + n] = f2bfbits(acc[i][j][r] + bias[n]);
            }
        }
    }
}

// ---------- scores: packed P = Q*K^T * scale (causal block-skip), 256x128 tiles ----------
__global__ __launch_bounds__(512)
void scores_mfma(const unsigned short* __restrict__ Qb, const unsigned short* __restrict__ Kb,
                 unsigned short* __restrict__ Pb, const float scale)
{
    const int3 b = xcd_swz();
    const int s0 = b.y*256, t0 = b.x*128;
    if (t0 >= s0 + 256) return;             // tile fully masked
    const unsigned short* Q  = Qb + (size_t)b.z*SD;
    const unsigned short* Km = Kb + (size_t)b.z*SD;
    unsigned short* P        = Pb + (size_t)b.z*PPB;
    DECL_PAIRS
    const int tid = threadIdx.x, lane = tid & 63, wave = tid >> 6;
    const unsigned short* ga[4]; const unsigned short* gb[2];
    mk_ga(Q,  DD, s0, wave, lane, ga);
    mk_gb(Km, DD, t0, wave, lane, gb);
    f32x4 acc[4][4] = {};
    gemm_loop8<false>(ga, gb, nullptr, nullptr, DD >> 6, acc, wave, lane, A_0, B_0, A_1, B_1);

    const int quad = lane >> 4, l15 = lane & 15;
    const int wr = (wave >> 1) * 64, wc = (wave & 1) * 64;
    #pragma unroll
    for (int i = 0; i < 4; ++i){
        #pragma unroll
        for (int r = 0; r < 4; ++r){
            const int s = s0 + wr + i*16 + quad*4 + r;
            const int width = rowWidth(s);
            unsigned short* pr = P + rowOff(s);
            #pragma unroll
            for (int j = 0; j < 4; ++j){
                const int t = t0 + wc + j*16 + l15;
                if (t < width) pr[t] = f2bfbits(acc[i][j][r] * scale);
            }
        }
    }
}

// ---------- causal softmax over packed rows ----------
__global__ __launch_bounds__(256)
void softmax_p(unsigned short* __restrict__ Pb)
{
    __shared__ float red[4];
    const int s = blockIdx.x;
    const int width = rowWidth(s);
    unsigned short* r = Pb + (size_t)blockIdx.y * PPB + rowOff(s);
    const int tid = threadIdx.x;
    float vals[8];
    float m = -1e30f;
    #pragma unroll
    for (int i = 0; i < 8; ++i){
        int t = tid + i*256;
        float v = -1e30f;
        if (t <= s) v = __uint_as_float(((unsigned)r[t]) << 16);
        vals[i] = v; m = fmaxf(m, v);
    }
    #pragma unroll
    for (int off = 32; off > 0; off >>= 1) m = fmaxf(m, __shfl_down(m, off, 64));
    if ((tid & 63) == 0) red[tid >> 6] = m;
    __syncthreads();
    const float M4 = fmaxf(fmaxf(red[0],red[1]), fmaxf(red[2],red[3]));
    __syncthreads();
    float ev[8]; float sum = 0.f;
    #pragma unroll
    for (int i = 0; i < 8; ++i){ ev[i] = __expf(vals[i] - M4); sum += ev[i]; }
    #pragma unroll
    for (int off = 32; off > 0; off >>= 1) sum += __shfl_down(sum, off, 64);
    if ((tid & 63) == 0) red[tid >> 6] = sum;
    __syncthreads();
    const float inv = 1.0f / (red[0]+red[1]+red[2]+red[3]);
    #pragma unroll
    for (int i = 0; i < 8; ++i){
        int t = tid + i*256;
        if (t < width) r[t] = f2bfbits(ev[i] * inv);
    }
}

// ---------- ctx = P @ V ; A=packed P (zpad for masked rows), B=VT[d][tok], 256x128 tiles ----------
__global__ __launch_bounds__(512)
void pv_mfma(const unsigned short* __restrict__ Pb, const unsigned short* __restrict__ VT,
             unsigned short* __restrict__ Cb, const unsigned short* __restrict__ zpad)
{
    const int3 b = xcd_swz();
    const int s0 = b.y*256, n0 = b.x*128;
    const unsigned short* P = Pb + (size_t)b.z*PPB;
    unsigned short* C       = Cb + (size_t)b.z*SD;
    const int bcol = b.z*SS;
    DECL_PAIRS
    const int tid = threadIdx.x, lane = tid & 63, wave = tid >> 6;
    const unsigned short* ga[4]; const unsigned short* gb[2]; int pw[4];
    #pragma unroll
    for (int c = 0; c < 4; ++c){
        const int mr = (wave*4 + c)*8 + (lane >> 3);
        const int gk = ((lane & 7) - mr) & 7;
        const int s = s0 + mr;
        pw[c] = rowWidth(s) - gk*8;                 // chunk valid iff koff < pw
        ga[c] = P + rowOff(s) + gk*8;
    }
    #pragma unroll
    for (int c = 0; c < 2; ++c){
        const int mr = (wave*2 + c)*8 + (lane >> 3);
        const int gk = ((lane & 7) - mr) & 7;
        gb[c] = VT + (size_t)(n0 + mr)*MM + bcol + gk*8;
    }
    f32x4 acc[4][4] = {};
    const int NT = (s0 + 256) >> 6;                 // 4..32, even
    gemm_loop8<true>(ga, gb, pw, zpad, NT, acc, wave, lane, A_0, B_0, A_1, B_1);

    const int quad = lane >> 4, l15 = lane & 15;
    const int wr = (wave >> 1) * 64, wc = (wave & 1) * 64;
    #pragma unroll
    for (int i = 0; i < 4; ++i){
        #pragma unroll
        for (int r = 0; r < 4; ++r){
            const int s = s0 + wr + i*16 + quad*4 + r;
            #pragma unroll
            for (int j = 0; j < 4; ++j){
                const int n = n0 + wc + j*16 + l15;
                C[(size_t)s*DD + n] = f2bfbits(acc[i][j][r]);
            }
        }
    }
}

extern "C" void kernel_launch(void* const* d_in, const int* in_sizes, int n_in,
                              void* d_out, int out_size, void* d_ws, size_t ws_size,
                              hipStream_t stream)
{
    (void)in_sizes; (void)n_in; (void)out_size;
    const float* x   = (const float*)d_in[0];
    const float* bq  = (const float*)d_in[2];
    const float* bk  = (const float*)d_in[4];
    const float* bv  = (const float*)d_in[6];
    const float* bo  = (const float*)d_in[8];
    const float* b1  = (const float*)d_in[10];
    const float* b2  = (const float*)d_in[12];
    const float* g1  = (const float*)d_in[13];
    const float* be1 = (const float*)d_in[14];
    const float* g2  = (const float*)d_in[15];
    const float* be2 = (const float*)d_in[16];
    float* outf = (float*)d_out;

    if (ws_size < (size_t)REQ_WS){
        sentinel_kernel<<<dim3((unsigned)(MD/256)), dim3(256), 0, stream>>>(outf, 1.0e9f);
        return;
    }

    unsigned short* wsb = (unsigned short*)d_ws;
    unsigned short* Qw  = wsb;                 // -> ctx
    unsigned short* Kw  = wsb + MD;            // \ -> Hf (fp32 spans K+VT)
    unsigned short* VTw = wsb + 2*MD;          // /
    unsigned short* Pw  = wsb + 3*MD;          // packed P -> mid
    unsigned short* WT  = wsb + WT_OFF;
    unsigned short* ZP  = wsb + ZP_OFF;
    float*          Hf  = (float*)Kw;
    unsigned short* CTX = Qw;
    unsigned short* MIDw= Pw;
    unsigned short* LN  = (unsigned short*)d_out;   // LN1/LN2 scratch in d_out

    WPack wp;
    static const int widx[6] = {1,3,5,7,9,11};
    for (int i = 0; i < 6; ++i){
        wp.w[i] = (const float*)d_in[widx[i]];
        wp.o[i] = WT + (size_t)i*DD*DD;
    }
    wp.zp = ZP;
    unsigned short* WqT = wp.o[0]; unsigned short* WkT = wp.o[1];
    unsigned short* WvT = wp.o[2]; unsigned short* WoT = wp.o[3];
    unsigned short* W1T = wp.o[4]; unsigned short* W2T = wp.o[5];

    const dim3 blk(256);
    const dim3 blk8(512);
    const float scale = 1.0f / sqrtf((float)SS);
    const dim3 gA8(DD/128, MM/256);   // (8,32)  = 256 blocks
    const dim3 gVT8(MM/128, DD/256);  // (64,4)  = 256 blocks

    wtrans<<<dim3(16,16,6), blk, 0, stream>>>(wp);
    ln_f32<<<dim3(MM), blk, 0, stream>>>(x, g1, be1, LN);
    // Q,K merged (512 blocks of 512 thr)
    gemm_qk<<<dim3(DD/128, MM/256, 2), blk8, 0, stream>>>(LN, WqT, WkT, bq, bk, Qw, Kw);
    // VT[d][tok] = WvT . LN^T (bias along m)
    gemm_mfma<false,false,false,true ><<<gVT8, blk8, 0, stream>>>(WvT, LN, bv, nullptr, VTw, nullptr, MM, DD, DD, DD);
    // attention (256x128 tiles)
    scores_mfma<<<dim3(SS/128, SS/256, BB), blk8, 0, stream>>>(Qw, Kw, Pw, scale);
    softmax_p<<<dim3(SS, BB), blk, 0, stream>>>(Pw);
    pv_mfma<<<dim3(DD/128, SS/256, BB), blk8, 0, stream>>>(Pw, VTw, CTX, ZP);
    // h = ctx*WoT^T + bo + x (fp32)
    gemm_mfma<false,true,true,false><<<gA8, blk8, 0, stream>>>(CTX, WoT, bo, x, nullptr, Hf, DD, DD, DD, DD);
    ln_f32<<<dim3(MM), blk, 0, stream>>>(Hf, g2, be2, LN);
    // mid = relu(LN*W1T^T + b1)
    gemm_mfma<true,false,false,false><<<gA8, blk8, 0, stream>>>(LN, W1T, b1, nullptr, MIDw, nullptr, DD, DD, DD, DD);
    // out = mid*W2T^T + b2 + h
    gemm_mfma<false,true,true,false><<<gA8, blk8, 0, stream>>>(MIDw, W2T, b2, Hf, nullptr, outf, DD, DD, DD, DD);
}

// Round 5
// 378.194 us; speedup vs baseline: 1.0442x; 1.0442x over previous
//
#include <hip/hip_runtime.h>
#include <math.h>

#define BB 4
#define SS 2048
#define DD 1024
#define MM (BB*SS)                   // 8192
#define SD ((size_t)SS*DD)
#define MD ((size_t)MM*DD)           // 8,388,608
#define PPB ((size_t)2162688)        // packed P elems per batch

// ws (bf16 elems): Q@0 | K@MD | VT@2MD | P@3MD (4*PPB) | WT (6*DD*DD) | zpad(16) | L (8192 f32)
#define WT_OFF (3*MD + 4*PPB)
#define ZP_OFF (WT_OFF + 6*(size_t)DD*DD)
#define LF_OFF (ZP_OFF + 16)
#define REQ_WS ((LF_OFF + 16384) * 2)

constexpr float LN_EPS = 1e-6f;

typedef __attribute__((ext_vector_type(8))) __bf16 bf16x8;
typedef __attribute__((ext_vector_type(4))) float f32x4;

__device__ __forceinline__ unsigned short f2bfbits(float f){
    unsigned u = __float_as_uint(f);
    u += 0x7FFFu + ((u >> 16) & 1u);   // RNE
    return (unsigned short)(u >> 16);
}
__device__ __forceinline__ int rowWidth(int s){ return ((s >> 6) + 1) << 6; }
__device__ __forceinline__ size_t rowOff(int s){
    int g = s >> 6;
    return (size_t)4096 * (size_t)((g * (g + 1)) >> 1) + (size_t)(s & 63) * (size_t)((g + 1) << 6);
}
// async global->LDS, 16B per lane; LDS dest = wave-uniform base + lane*16
__device__ __forceinline__ void gl_lds(const unsigned short* g, unsigned short* l){
    __builtin_amdgcn_global_load_lds(
        (const __attribute__((address_space(1))) unsigned int*)g,
        (__attribute__((address_space(3))) unsigned int*)l, 16, 0, 0);
}

// XCD-aware bijective block swizzle (T1) — DENSE kernels only. For causal
// kernels (scores/pv) the per-block work is y-dependent and chunking creates
// up to 2.6x inter-XCD load imbalance; those use natural round-robin instead.
__device__ __forceinline__ int3 xcd_swz(){
    const int gx = gridDim.x, gy = gridDim.y, gz = gridDim.z;
    const int n = gx * gy * gz;
    int lin = blockIdx.x + gx * (blockIdx.y + gy * blockIdx.z);
    const int cpx = n >> 3;                 // n % 8 == 0 for all swizzled launches
    lin = (lin & 7) * cpx + (lin >> 3);     // bijection: XCD (lin&7) owns chunk
    int3 r;
    r.x = lin % gx; lin /= gx;
    r.y = lin % gy;
    r.z = lin / gy;
    return r;
}

__global__ __launch_bounds__(256)
void sentinel_kernel(float* __restrict__ out, const float val){
    out[(size_t)blockIdx.x * 256 + threadIdx.x] = val;
}

// ---------- weight transpose W[K][N] f32 -> WT[N][K] bf16 ; zeroes zpad + L ----------
struct WPack { const float* w[6]; unsigned short* o[6]; unsigned short* zp; float* lf; };
__global__ __launch_bounds__(256)
void wtrans(WPack wp)
{
    __shared__ float Ts[64][65];
    const float* W = wp.w[blockIdx.z];
    unsigned short* WT = wp.o[blockIdx.z];
    const int r0 = blockIdx.y*64, c0 = blockIdx.x*64;
    const int tid = threadIdx.x;
    if (blockIdx.x == 0 && blockIdx.y == 0 && blockIdx.z == 0 && tid < 16) wp.zp[tid] = 0;
    // zero the softmax row-sum accumulator L[8192] (f32) before scores runs
    if (blockIdx.y == 0 && blockIdx.z == 0){
        float2 z2 = {0.f, 0.f};
        ((float2*)wp.lf)[blockIdx.x*256 + tid] = z2;
    }
    #pragma unroll
    for (int i = 0; i < 16; ++i){
        int lin = tid + i*256;
        int r = lin >> 6, c = lin & 63;
        Ts[r][c] = W[(size_t)(r0+r)*DD + c0+c];
    }
    __syncthreads();
    #pragma unroll
    for (int i = 0; i < 16; ++i){
        int lin = tid + i*256;
        int r = lin >> 6, c = lin & 63;
        WT[(size_t)(c0+r)*DD + r0+c] = f2bfbits(Ts[c][r]);
    }
}

// ---------- LayerNorm: fp32 in -> bf16 out ----------
__global__ __launch_bounds__(256)
void ln_f32(const float* __restrict__ x, const float* __restrict__ gamma,
            const float* __restrict__ beta, unsigned short* __restrict__ out)
{
    __shared__ float red[4];
    const int row = blockIdx.x;
    const int tid = threadIdx.x;
    float4 xv = ((const float4*)(x + (size_t)row*DD))[tid];
    float v[4] = {xv.x, xv.y, xv.z, xv.w};
    float s = v[0]+v[1]+v[2]+v[3];
    #pragma unroll
    for (int off = 32; off > 0; off >>= 1) s += __shfl_down(s, off, 64);
    if ((tid & 63) == 0) red[tid >> 6] = s;
    __syncthreads();
    const float mean = (red[0]+red[1]+red[2]+red[3]) * (1.0f/DD);
    __syncthreads();
    float q = 0.f;
    #pragma unroll
    for (int i = 0; i < 4; ++i){ float d = v[i]-mean; q += d*d; }
    #pragma unroll
    for (int off = 32; off > 0; off >>= 1) q += __shfl_down(q, off, 64);
    if ((tid & 63) == 0) red[tid >> 6] = q;
    __syncthreads();
    const float var = (red[0]+red[1]+red[2]+red[3]) * (1.0f/(DD-1));
    const float inv = 1.0f/(sqrtf(var) + LN_EPS);
    float4 g4 = ((const float4*)gamma)[tid];
    float4 b4 = ((const float4*)beta)[tid];
    ushort4 o;
    o.x = f2bfbits(g4.x*(v[0]-mean)*inv + b4.x);
    o.y = f2bfbits(g4.y*(v[1]-mean)*inv + b4.y);
    o.z = f2bfbits(g4.z*(v[2]-mean)*inv + b4.z);
    o.w = f2bfbits(g4.w*(v[3]-mean)*inv + b4.w);
    ((ushort4*)(out + (size_t)row*DD))[tid] = o;
}

// =========== MFMA GEMM core: C[128,128] tile of A[M,K]*B[N,K]^T ===========
// BK=64, 4 waves 2x2, each 64x64. global_load_lds staging, granule-rotated LDS.
// LDS tile: row m (64 shorts), granule g stored at slot (g+m)&7.
// (R1-measured-best structure: 731 TF on gemm_qk; deeper pipelining attempts
//  in R3/R4 were null/negative — m196/m233 pattern.)
template<bool RELU, bool RES, bool OUTF, bool BIAS_M>
__device__ __forceinline__ void gemm_core(
    const unsigned short* __restrict__ A, const unsigned short* __restrict__ B,
    const float* __restrict__ bias, const float* __restrict__ resF,
    unsigned short* __restrict__ outB, float* __restrict__ outF,
    const int N, const int K, const int lda, const int ldb,
    const int m0, const int n0,
    unsigned short* As, unsigned short* Bs)
{
    const int tid = threadIdx.x, lane = tid & 63, wave = tid >> 6;
    const int wm = ((wave >> 1) & 1) * 64, wn = (wave & 1) * 64;
    const int quad = lane >> 4, l15 = lane & 15;
    const unsigned short* ga[4]; const unsigned short* gb[4];
    #pragma unroll
    for (int c = 0; c < 4; ++c){
        const int mr = (wave*4 + c)*8 + (lane >> 3);
        const int gk = ((lane & 7) - mr) & 7;
        ga[c] = A + (size_t)(m0 + mr)*lda + gk*8;
        gb[c] = B + (size_t)(n0 + mr)*ldb + gk*8;
    }
    f32x4 acc[4][4] = {};
    for (int k0 = 0; k0 < K; k0 += 64){
        #pragma unroll
        for (int c = 0; c < 4; ++c){
            gl_lds(ga[c] + k0, &As[(wave*4+c)*512]);
            gl_lds(gb[c] + k0, &Bs[(wave*4+c)*512]);
        }
        __syncthreads();
        #pragma unroll
        for (int kk = 0; kk < 2; ++kk){
            bf16x8 af[4], bfr[4];
            #pragma unroll
            for (int t = 0; t < 4; ++t){
                const int ra = wm + t*16 + l15, rb = wn + t*16 + l15, gi = kk*4 + quad;
                af[t]  = *(const bf16x8*)&As[ra*64 + (((gi + ra) & 7) << 3)];
                bfr[t] = *(const bf16x8*)&Bs[rb*64 + (((gi + rb) & 7) << 3)];
            }
            #pragma unroll
            for (int i = 0; i < 4; ++i)
                #pragma unroll
                for (int j = 0; j < 4; ++j)
                    acc[i][j] = __builtin_amdgcn_mfma_f32_16x16x32_bf16(af[i], bfr[j], acc[i][j], 0, 0, 0);
        }
        __syncthreads();
    }
    #pragma unroll
    for (int i = 0; i < 4; ++i){
        #pragma unroll
        for (int r = 0; r < 4; ++r){
            const int m = m0 + wm + i*16 + quad*4 + r;
            const float bm = BIAS_M ? bias[m] : 0.f;
            #pragma unroll
            for (int j = 0; j < 4; ++j){
                const int n = n0 + wn + j*16 + l15;
                float v = acc[i][j][r] + (BIAS_M ? bm : bias[n]);
                if constexpr (RELU) v = fmaxf(v, 0.f);
                if constexpr (RES) v += resF[(size_t)m*N + n];
                if constexpr (OUTF) outF[(size_t)m*N + n] = v;
                else outB[(size_t)m*N + n] = f2bfbits(v);
            }
        }
    }
}

// generic single GEMM
template<bool RELU, bool RES, bool OUTF, bool BIAS_M>
__global__ __launch_bounds__(256)
void gemm_mfma(const unsigned short* __restrict__ A, const unsigned short* __restrict__ B,
               const float* __restrict__ bias, const float* __restrict__ resF,
               unsigned short* __restrict__ outB, float* __restrict__ outF,
               const int N, const int K, const int lda, const int ldb)
{
    __shared__ unsigned short As[128*64];
    __shared__ unsigned short Bs[128*64];
    const int3 b = xcd_swz();
    gemm_core<RELU,RES,OUTF,BIAS_M>(A, B, bias, resF, outB, outF, N, K, lda, ldb,
                                    b.y*128, b.x*128, As, Bs);
}

// merged Q+K projection (z=0 -> Q, z=1 -> K)
__global__ __launch_bounds__(256)
void gemm_qk(const unsigned short* __restrict__ LN,
             const unsigned short* __restrict__ WqT, const unsigned short* __restrict__ WkT,
             const float* __restrict__ bq, const float* __restrict__ bk,
             unsigned short* __restrict__ Qw, unsigned short* __restrict__ Kw)
{
    __shared__ unsigned short As[128*64];
    __shared__ unsigned short Bs[128*64];
    const int3 b = xcd_swz();
    const bool isK = (b.z != 0);
    gemm_core<false,false,false,false>(LN, isK ? WkT : WqT, isK ? bk : bq, nullptr,
                                       isK ? Kw : Qw, nullptr, DD, DD, DD, DD,
                                       b.y*128, b.x*128, As, Bs);
}

// ---------- scores: packed P = exp(Q*K^T * scale), causal, UNNORMALIZED ----------
// Fused softmax (no max-subtraction: |S| <~ 4 with LN'd inputs -> exp is f32-safe).
// Row sums accumulate into Lf[b*SS+s] via 16-lane shuffle + one atomicAdd/row.
// pv divides by Lf in its epilogue. NO xcd swizzle (causal load balance).
__global__ __launch_bounds__(256)
void scores_mfma(const unsigned short* __restrict__ Qb, const unsigned short* __restrict__ Kb,
                 unsigned short* __restrict__ Pb, float* __restrict__ Lf, const float scale)
{
    const int s0 = blockIdx.y*128, t0 = blockIdx.x*128;
    if (t0 > s0) return;
    const unsigned short* Q  = Qb + (size_t)blockIdx.z*SD;
    const unsigned short* Km = Kb + (size_t)blockIdx.z*SD;
    unsigned short* P        = Pb + (size_t)blockIdx.z*PPB;
    float* L                 = Lf + (size_t)blockIdx.z*SS;
    __shared__ unsigned short As[128*64];
    __shared__ unsigned short Bs[128*64];
    const int tid = threadIdx.x, lane = tid & 63, wave = tid >> 6;
    const int wm = ((wave >> 1) & 1) * 64, wn = (wave & 1) * 64;
    const int quad = lane >> 4, l15 = lane & 15;
    const unsigned short* ga[4]; const unsigned short* gb[4];
    #pragma unroll
    for (int c = 0; c < 4; ++c){
        const int mr = (wave*4 + c)*8 + (lane >> 3);
        const int gk = ((lane & 7) - mr) & 7;
        ga[c] = Q  + (size_t)(s0 + mr)*DD + gk*8;
        gb[c] = Km + (size_t)(t0 + mr)*DD + gk*8;
    }
    f32x4 acc[4][4] = {};
    for (int k0 = 0; k0 < DD; k0 += 64){
        #pragma unroll
        for (int c = 0; c < 4; ++c){
            gl_lds(ga[c] + k0, &As[(wave*4+c)*512]);
            gl_lds(gb[c] + k0, &Bs[(wave*4+c)*512]);
        }
        __syncthreads();
        #pragma unroll
        for (int kk = 0; kk < 2; ++kk){
            bf16x8 af[4], bfr[4];
            #pragma unroll
            for (int t = 0; t < 4; ++t){
                const int ra = wm + t*16 + l15, rb = wn + t*16 + l15, gi = kk*4 + quad;
                af[t]  = *(const bf16x8*)&As[ra*64 + (((gi + ra) & 7) << 3)];
                bfr[t] = *(const bf16x8*)&Bs[rb*64 + (((gi + rb) & 7) << 3)];
            }
            #pragma unroll
            for (int i = 0; i < 4; ++i)
                #pragma unroll
                for (int j = 0; j < 4; ++j)
                    acc[i][j] = __builtin_amdgcn_mfma_f32_16x16x32_bf16(af[i], bfr[j], acc[i][j], 0, 0, 0);
        }
        __syncthreads();
    }
    #pragma unroll
    for (int i = 0; i < 4; ++i){
        #pragma unroll
        for (int r = 0; r < 4; ++r){
            const int s = s0 + wm + i*16 + quad*4 + r;
            const int width = rowWidth(s);
            unsigned short* pr = P + rowOff(s);
            float psum = 0.f;
            if (t0 + wn < width){                    // 64-chunk uniform in/out
                #pragma unroll
                for (int j = 0; j < 4; ++j){
                    const int t = t0 + wn + j*16 + l15;
                    const float e = (t <= s) ? __expf(acc[i][j][r] * scale) : 0.f;
                    pr[t] = f2bfbits(e);
                    psum += e;
                }
                // reduce across the 16 lanes (l15) sharing row s
                #pragma unroll
                for (int off = 8; off > 0; off >>= 1) psum += __shfl_xor(psum, off, 64);
                if (l15 == 0) atomicAdd(&L[s], psum);
            }
        }
    }
}

// ---------- ctx = (P @ V) / l ; A=packed unnormalized P, B=VT[d][tok] ----------
// NO xcd swizzle (variable-NT causal work -> natural round-robin balances XCDs).
__global__ __launch_bounds__(256)
void pv_mfma(const unsigned short* __restrict__ Pb, const unsigned short* __restrict__ VT,
             unsigned short* __restrict__ Cb, const unsigned short* __restrict__ zpad,
             const float* __restrict__ Lf)
{
    const int s0 = blockIdx.y*128, n0 = blockIdx.x*128;
    const unsigned short* P = Pb + (size_t)blockIdx.z*PPB;
    unsigned short* C       = Cb + (size_t)blockIdx.z*SD;
    const float* L          = Lf + (size_t)blockIdx.z*SS;
    const int bcol = blockIdx.z*SS;
    __shared__ unsigned short As[128*64];
    __shared__ unsigned short Bs[128*64];
    const int tid = threadIdx.x, lane = tid & 63, wave = tid >> 6;
    const int wm = ((wave >> 1) & 1) * 64, wn = (wave & 1) * 64;
    const int quad = lane >> 4, l15 = lane & 15;
    const unsigned short* ga[4]; const unsigned short* gb[4]; int pw[4];
    #pragma unroll
    for (int c = 0; c < 4; ++c){
        const int mr = (wave*4 + c)*8 + (lane >> 3);
        const int gk = ((lane & 7) - mr) & 7;
        const int s = s0 + mr;
        pw[c] = rowWidth(s) - gk*8;                 // valid iff k0 < pw
        ga[c] = P + rowOff(s) + gk*8;
        gb[c] = VT + (size_t)(n0 + mr)*MM + bcol + gk*8;
    }
    f32x4 acc[4][4] = {};
    const int kmax = s0 + 128;
    for (int k0 = 0; k0 < kmax; k0 += 64){
        #pragma unroll
        for (int c = 0; c < 4; ++c){
            const unsigned short* gp = (k0 < pw[c]) ? (ga[c] + k0) : zpad;
            gl_lds(gp, &As[(wave*4+c)*512]);
            gl_lds(gb[c] + k0, &Bs[(wave*4+c)*512]);
        }
        __syncthreads();
        #pragma unroll
        for (int kk = 0; kk < 2; ++kk){
            bf16x8 af[4], bfr[4];
            #pragma unroll
            for (int t = 0; t < 4; ++t){
                const int ra = wm + t*16 + l15, rb = wn + t*16 + l15, gi = kk*4 + quad;
                af[t]  = *(const bf16x8*)&As[ra*64 + (((gi + ra) & 7) << 3)];
                bfr[t] = *(const bf16x8*)&Bs[rb*64 + (((gi + rb) & 7) << 3)];
            }
            #pragma unroll
            for (int i = 0; i < 4; ++i)
                #pragma unroll
                for (int j = 0; j < 4; ++j)
                    acc[i][j] = __builtin_amdgcn_mfma_f32_16x16x32_bf16(af[i], bfr[j], acc[i][j], 0, 0, 0);
        }
        __syncthreads();
    }
    #pragma unroll
    for (int i = 0; i < 4; ++i){
        #pragma unroll
        for (int r = 0; r < 4; ++r){
            const int s = s0 + wm + i*16 + quad*4 + r;
            const float linv = 1.0f / L[s];
            #pragma unroll
            for (int j = 0; j < 4; ++j){
                const int n = n0 + wn + j*16 + l15;
                C[(size_t)s*DD + n] = f2bfbits(acc[i][j][r] * linv);
            }
        }
    }
}

extern "C" void kernel_launch(void* const* d_in, const int* in_sizes, int n_in,
                              void* d_out, int out_size, void* d_ws, size_t ws_size,
                              hipStream_t stream)
{
    (void)in_sizes; (void)n_in; (void)out_size;
    const float* x   = (const float*)d_in[0];
    const float* bq  = (const float*)d_in[2];
    const float* bk  = (const float*)d_in[4];
    const float* bv  = (const float*)d_in[6];
    const float* bo  = (const float*)d_in[8];
    const float* b1  = (const float*)d_in[10];
    const float* b2  = (const float*)d_in[12];
    const float* g1  = (const float*)d_in[13];
    const float* be1 = (const float*)d_in[14];
    const float* g2  = (const float*)d_in[15];
    const float* be2 = (const float*)d_in[16];
    float* outf = (float*)d_out;

    if (ws_size < (size_t)REQ_WS){
        sentinel_kernel<<<dim3((unsigned)(MD/256)), dim3(256), 0, stream>>>(outf, 1.0e9f);
        return;
    }

    unsigned short* wsb = (unsigned short*)d_ws;
    unsigned short* Qw  = wsb;                 // -> ctx
    unsigned short* Kw  = wsb + MD;            // \ -> Hf (fp32 spans K+VT)
    unsigned short* VTw = wsb + 2*MD;          // /
    unsigned short* Pw  = wsb + 3*MD;          // packed P -> mid
    unsigned short* WT  = wsb + WT_OFF;
    unsigned short* ZP  = wsb + ZP_OFF;
    float*          Lf  = (float*)(wsb + LF_OFF);
    float*          Hf  = (float*)Kw;
    unsigned short* CTX = Qw;
    unsigned short* MIDw= Pw;
    unsigned short* LN  = (unsigned short*)d_out;   // LN1/LN2 scratch in d_out

    WPack wp;
    static const int widx[6] = {1,3,5,7,9,11};
    for (int i = 0; i < 6; ++i){
        wp.w[i] = (const float*)d_in[widx[i]];
        wp.o[i] = WT + (size_t)i*DD*DD;
    }
    wp.zp = ZP;
    wp.lf = Lf;
    unsigned short* WqT = wp.o[0]; unsigned short* WkT = wp.o[1];
    unsigned short* WvT = wp.o[2]; unsigned short* WoT = wp.o[3];
    unsigned short* W1T = wp.o[4]; unsigned short* W2T = wp.o[5];

    const dim3 blk(256);
    const float scale = 1.0f / sqrtf((float)SS);
    const dim3 gA(DD/128, MM/128);    // (8,64)
    const dim3 gVT(MM/128, DD/128);   // (64,8)

    wtrans<<<dim3(16,16,6), blk, 0, stream>>>(wp);
    ln_f32<<<dim3(MM), blk, 0, stream>>>(x, g1, be1, LN);
    // Q,K merged (1024 blocks)
    gemm_qk<<<dim3(DD/128, MM/128, 2), blk, 0, stream>>>(LN, WqT, WkT, bq, bk, Qw, Kw);
    // VT[d][tok] = WvT . LN^T (bias along m)
    gemm_mfma<false,false,false,true ><<<gVT, blk, 0, stream>>>(WvT, LN, bv, nullptr, VTw, nullptr, MM, DD, DD, DD);
    // attention: fused exp-scores (+row sums) then PV (/rowsum). No softmax pass.
    scores_mfma<<<dim3(SS/128, SS/128, BB), blk, 0, stream>>>(Qw, Kw, Pw, Lf, scale);
    pv_mfma<<<dim3(DD/128, SS/128, BB), blk, 0, stream>>>(Pw, VTw, CTX, ZP, Lf);
    // h = ctx*WoT^T + bo + x (fp32)
    gemm_mfma<false,true,true,false><<<gA, blk, 0, stream>>>(CTX, WoT, bo, x, nullptr, Hf, DD, DD, DD, DD);
    ln_f32<<<dim3(MM), blk, 0, stream>>>(Hf, g2, be2, LN);
    // mid = relu(LN*W1T^T + b1)
    gemm_mfma<true,false,false,false><<<gA, blk, 0, stream>>>(LN, W1T, b1, nullptr, MIDw, nullptr, DD, DD, DD, DD);
    // out = mid*W2T^T + b2 + h
    gemm_mfma<false,true,true,false><<<gA, blk, 0, stream>>>(MIDw, W2T, b2, Hf, nullptr, outf, DD, DD, DD, DD);
}

// Round 6
// 369.367 us; speedup vs baseline: 1.0691x; 1.0239x over previous
//
#include <hip/hip_runtime.h>
#include <math.h>

#define BB 4
#define SS 2048
#define DD 1024
#define MM (BB*SS)                   // 8192
#define SD ((size_t)SS*DD)
#define MD ((size_t)MM*DD)           // 8,388,608
#define PPB ((size_t)2162688)        // packed P elems per batch

// ws (bf16 elems): Q@0 | K@MD | VT@2MD | P@3MD (4*PPB) | WT (6*DD*DD) | zpad(16) | L (8192 f32)
#define WT_OFF (3*MD + 4*PPB)
#define ZP_OFF (WT_OFF + 6*(size_t)DD*DD)
#define LF_OFF (ZP_OFF + 16)
#define REQ_WS ((LF_OFF + 16384) * 2)

constexpr float LN_EPS = 1e-6f;

typedef __attribute__((ext_vector_type(8))) __bf16 bf16x8;
typedef __attribute__((ext_vector_type(4))) float f32x4;

__device__ __forceinline__ unsigned short f2bfbits(float f){
    unsigned u = __float_as_uint(f);
    u += 0x7FFFu + ((u >> 16) & 1u);   // RNE
    return (unsigned short)(u >> 16);
}
__device__ __forceinline__ int rowWidth(int s){ return ((s >> 6) + 1) << 6; }
__device__ __forceinline__ size_t rowOff(int s){
    int g = s >> 6;
    return (size_t)4096 * (size_t)((g * (g + 1)) >> 1) + (size_t)(s & 63) * (size_t)((g + 1) << 6);
}
// async global->LDS, 16B per lane; LDS dest = wave-uniform base + lane*16
__device__ __forceinline__ void gl_lds(const unsigned short* g, unsigned short* l){
    __builtin_amdgcn_global_load_lds(
        (const __attribute__((address_space(1))) unsigned int*)g,
        (__attribute__((address_space(3))) unsigned int*)l, 16, 0, 0);
}

// XCD-aware bijective block swizzle (T1) — uniform-work launches only.
__device__ __forceinline__ int3 xcd_swz(){
    const int gx = gridDim.x, gy = gridDim.y, gz = gridDim.z;
    const int n = gx * gy * gz;
    int lin = blockIdx.x + gx * (blockIdx.y + gy * blockIdx.z);
    const int cpx = n >> 3;                 // n % 8 == 0 for all swizzled launches
    lin = (lin & 7) * cpx + (lin >> 3);     // bijection: XCD (lin&7) owns chunk
    int3 r;
    r.x = lin % gx; lin /= gx;
    r.y = lin % gy;
    r.z = lin / gy;
    return r;
}

__global__ __launch_bounds__(256)
void sentinel_kernel(float* __restrict__ out, const float val){
    out[(size_t)blockIdx.x * 256 + threadIdx.x] = val;
}

// ---------- weight transpose W[K][N] f32 -> WT[N][K] bf16 ; zeroes zpad + L ----------
struct WPack { const float* w[6]; unsigned short* o[6]; unsigned short* zp; float* lf; };
__global__ __launch_bounds__(256)
void wtrans(WPack wp)
{
    __shared__ float Ts[64][65];
    const float* W = wp.w[blockIdx.z];
    unsigned short* WT = wp.o[blockIdx.z];
    const int r0 = blockIdx.y*64, c0 = blockIdx.x*64;
    const int tid = threadIdx.x;
    if (blockIdx.x == 0 && blockIdx.y == 0 && blockIdx.z == 0 && tid < 16) wp.zp[tid] = 0;
    // zero the softmax row-sum accumulator L[8192] (f32) before scores runs
    if (blockIdx.y == 0 && blockIdx.z == 0){
        float2 z2 = {0.f, 0.f};
        ((float2*)wp.lf)[blockIdx.x*256 + tid] = z2;
    }
    #pragma unroll
    for (int i = 0; i < 16; ++i){
        int lin = tid + i*256;
        int r = lin >> 6, c = lin & 63;
        Ts[r][c] = W[(size_t)(r0+r)*DD + c0+c];
    }
    __syncthreads();
    #pragma unroll
    for (int i = 0; i < 16; ++i){
        int lin = tid + i*256;
        int r = lin >> 6, c = lin & 63;
        WT[(size_t)(c0+r)*DD + r0+c] = f2bfbits(Ts[c][r]);
    }
}

// ---------- LayerNorm: fp32 in -> bf16 out ----------
__global__ __launch_bounds__(256)
void ln_f32(const float* __restrict__ x, const float* __restrict__ gamma,
            const float* __restrict__ beta, unsigned short* __restrict__ out)
{
    __shared__ float red[4];
    const int row = blockIdx.x;
    const int tid = threadIdx.x;
    float4 xv = ((const float4*)(x + (size_t)row*DD))[tid];
    float v[4] = {xv.x, xv.y, xv.z, xv.w};
    float s = v[0]+v[1]+v[2]+v[3];
    #pragma unroll
    for (int off = 32; off > 0; off >>= 1) s += __shfl_down(s, off, 64);
    if ((tid & 63) == 0) red[tid >> 6] = s;
    __syncthreads();
    const float mean = (red[0]+red[1]+red[2]+red[3]) * (1.0f/DD);
    __syncthreads();
    float q = 0.f;
    #pragma unroll
    for (int i = 0; i < 4; ++i){ float d = v[i]-mean; q += d*d; }
    #pragma unroll
    for (int off = 32; off > 0; off >>= 1) q += __shfl_down(q, off, 64);
    if ((tid & 63) == 0) red[tid >> 6] = q;
    __syncthreads();
    const float var = (red[0]+red[1]+red[2]+red[3]) * (1.0f/(DD-1));
    const float inv = 1.0f/(sqrtf(var) + LN_EPS);
    float4 g4 = ((const float4*)gamma)[tid];
    float4 b4 = ((const float4*)beta)[tid];
    ushort4 o;
    o.x = f2bfbits(g4.x*(v[0]-mean)*inv + b4.x);
    o.y = f2bfbits(g4.y*(v[1]-mean)*inv + b4.y);
    o.z = f2bfbits(g4.z*(v[2]-mean)*inv + b4.z);
    o.w = f2bfbits(g4.w*(v[3]-mean)*inv + b4.w);
    ((ushort4*)(out + (size_t)row*DD))[tid] = o;
}

// =========== MFMA GEMM core: C[128,128] tile of A[M,K]*B[N,K]^T ===========
// BK=64, 4 waves 2x2, each 64x64. global_load_lds staging, granule-rotated LDS.
// (R1-measured-best structure; deeper pipelining attempts R2-R4 were null/neg.)
template<bool RELU, bool RES, bool OUTF, bool BIAS_M>
__device__ __forceinline__ void gemm_core(
    const unsigned short* __restrict__ A, const unsigned short* __restrict__ B,
    const float* __restrict__ bias, const float* __restrict__ resF,
    unsigned short* __restrict__ outB, float* __restrict__ outF,
    const int N, const int K, const int lda, const int ldb,
    const int m0, const int n0,
    unsigned short* As, unsigned short* Bs)
{
    const int tid = threadIdx.x, lane = tid & 63, wave = tid >> 6;
    const int wm = ((wave >> 1) & 1) * 64, wn = (wave & 1) * 64;
    const int quad = lane >> 4, l15 = lane & 15;
    const unsigned short* ga[4]; const unsigned short* gb[4];
    #pragma unroll
    for (int c = 0; c < 4; ++c){
        const int mr = (wave*4 + c)*8 + (lane >> 3);
        const int gk = ((lane & 7) - mr) & 7;
        ga[c] = A + (size_t)(m0 + mr)*lda + gk*8;
        gb[c] = B + (size_t)(n0 + mr)*ldb + gk*8;
    }
    f32x4 acc[4][4] = {};
    for (int k0 = 0; k0 < K; k0 += 64){
        #pragma unroll
        for (int c = 0; c < 4; ++c){
            gl_lds(ga[c] + k0, &As[(wave*4+c)*512]);
            gl_lds(gb[c] + k0, &Bs[(wave*4+c)*512]);
        }
        __syncthreads();
        #pragma unroll
        for (int kk = 0; kk < 2; ++kk){
            bf16x8 af[4], bfr[4];
            #pragma unroll
            for (int t = 0; t < 4; ++t){
                const int ra = wm + t*16 + l15, rb = wn + t*16 + l15, gi = kk*4 + quad;
                af[t]  = *(const bf16x8*)&As[ra*64 + (((gi + ra) & 7) << 3)];
                bfr[t] = *(const bf16x8*)&Bs[rb*64 + (((gi + rb) & 7) << 3)];
            }
            #pragma unroll
            for (int i = 0; i < 4; ++i)
                #pragma unroll
                for (int j = 0; j < 4; ++j)
                    acc[i][j] = __builtin_amdgcn_mfma_f32_16x16x32_bf16(af[i], bfr[j], acc[i][j], 0, 0, 0);
        }
        __syncthreads();
    }
    #pragma unroll
    for (int i = 0; i < 4; ++i){
        #pragma unroll
        for (int r = 0; r < 4; ++r){
            const int m = m0 + wm + i*16 + quad*4 + r;
            const float bm = BIAS_M ? bias[m] : 0.f;
            #pragma unroll
            for (int j = 0; j < 4; ++j){
                const int n = n0 + wn + j*16 + l15;
                float v = acc[i][j][r] + (BIAS_M ? bm : bias[n]);
                if constexpr (RELU) v = fmaxf(v, 0.f);
                if constexpr (RES) v += resF[(size_t)m*N + n];
                if constexpr (OUTF) outF[(size_t)m*N + n] = v;
                else outB[(size_t)m*N + n] = f2bfbits(v);
            }
        }
    }
}

// generic single GEMM
template<bool RELU, bool RES, bool OUTF, bool BIAS_M>
__global__ __launch_bounds__(256)
void gemm_mfma(const unsigned short* __restrict__ A, const unsigned short* __restrict__ B,
               const float* __restrict__ bias, const float* __restrict__ resF,
               unsigned short* __restrict__ outB, float* __restrict__ outF,
               const int N, const int K, const int lda, const int ldb)
{
    __shared__ unsigned short As[128*64];
    __shared__ unsigned short Bs[128*64];
    const int3 b = xcd_swz();
    gemm_core<RELU,RES,OUTF,BIAS_M>(A, B, bias, resF, outB, outF, N, K, lda, ldb,
                                    b.y*128, b.x*128, As, Bs);
}

// ---------- fused Q/K/VT projections: 1536 uniform tiles in ONE launch ----------
// id<512: Q tile; id<1024: K tile; else VT tile. All 16 K-iter, uniform cost ->
// chunked XCD swizzle is balanced AND local; 6 blocks/CU improves latency hiding.
__global__ __launch_bounds__(256)
void proj_fused(const unsigned short* __restrict__ LN,
                const unsigned short* __restrict__ WqT, const unsigned short* __restrict__ WkT,
                const unsigned short* __restrict__ WvT,
                const float* __restrict__ bq, const float* __restrict__ bk,
                const float* __restrict__ bv,
                unsigned short* __restrict__ Qw, unsigned short* __restrict__ Kw,
                unsigned short* __restrict__ VTw)
{
    __shared__ unsigned short As[128*64];
    __shared__ unsigned short Bs[128*64];
    const int lin = blockIdx.x;                    // 1536
    const int id = (lin & 7) * 192 + (lin >> 3);   // chunked XCD swizzle
    if (id < 1024){
        const bool isK = (id >= 512);
        const int q = id & 511;
        const int n0 = (q & 7) * 128, m0 = (q >> 3) * 128;   // n over DD, m over MM
        gemm_core<false,false,false,false>(LN, isK ? WkT : WqT, isK ? bk : bq, nullptr,
                                           isK ? Kw : Qw, nullptr, DD, DD, DD, DD,
                                           m0, n0, As, Bs);
    } else {
        const int q = id - 1024;
        const int n0 = (q & 63) * 128, m0 = (q >> 6) * 128;  // n over MM, m over DD
        gemm_core<false,false,false,true>(WvT, LN, bv, nullptr, VTw, nullptr,
                                          MM, DD, DD, DD, m0, n0, As, Bs);
    }
}

// ---------- scores: packed P = exp(Q*K^T * scale), causal, UNNORMALIZED ----------
// Triangular-packed launch: exactly 544 active tiles (no masked-block waste),
// uniform cost -> chunked XCD swizzle balanced + local. Row sums -> atomicAdd L.
__global__ __launch_bounds__(256)
void scores_mfma(const unsigned short* __restrict__ Qb, const unsigned short* __restrict__ Kb,
                 unsigned short* __restrict__ Pb, float* __restrict__ Lf, const float scale)
{
    const int lin = blockIdx.x;                    // 544 = 4 * 136
    const int id = (lin & 7) * 68 + (lin >> 3);    // chunked XCD swizzle
    const int z = id / 136;
    const int idx = id - z * 136;
    int y = (int)((sqrtf(8.f * (float)idx + 1.f) - 1.f) * 0.5f);
    while ((y + 1) * (y + 2) / 2 <= idx) ++y;      // guard float error
    while (y * (y + 1) / 2 > idx) --y;
    const int x = idx - y * (y + 1) / 2;           // x <= y
    const int s0 = y * 128, t0 = x * 128;

    const unsigned short* Q  = Qb + (size_t)z*SD;
    const unsigned short* Km = Kb + (size_t)z*SD;
    unsigned short* P        = Pb + (size_t)z*PPB;
    float* L                 = Lf + (size_t)z*SS;
    __shared__ unsigned short As[128*64];
    __shared__ unsigned short Bs[128*64];
    const int tid = threadIdx.x, lane = tid & 63, wave = tid >> 6;
    const int wm = ((wave >> 1) & 1) * 64, wn = (wave & 1) * 64;
    const int quad = lane >> 4, l15 = lane & 15;
    const unsigned short* ga[4]; const unsigned short* gb[4];
    #pragma unroll
    for (int c = 0; c < 4; ++c){
        const int mr = (wave*4 + c)*8 + (lane >> 3);
        const int gk = ((lane & 7) - mr) & 7;
        ga[c] = Q  + (size_t)(s0 + mr)*DD + gk*8;
        gb[c] = Km + (size_t)(t0 + mr)*DD + gk*8;
    }
    f32x4 acc[4][4] = {};
    for (int k0 = 0; k0 < DD; k0 += 64){
        #pragma unroll
        for (int c = 0; c < 4; ++c){
            gl_lds(ga[c] + k0, &As[(wave*4+c)*512]);
            gl_lds(gb[c] + k0, &Bs[(wave*4+c)*512]);
        }
        __syncthreads();
        #pragma unroll
        for (int kk = 0; kk < 2; ++kk){
            bf16x8 af[4], bfr[4];
            #pragma unroll
            for (int t = 0; t < 4; ++t){
                const int ra = wm + t*16 + l15, rb = wn + t*16 + l15, gi = kk*4 + quad;
                af[t]  = *(const bf16x8*)&As[ra*64 + (((gi + ra) & 7) << 3)];
                bfr[t] = *(const bf16x8*)&Bs[rb*64 + (((gi + rb) & 7) << 3)];
            }
            #pragma unroll
            for (int i = 0; i < 4; ++i)
                #pragma unroll
                for (int j = 0; j < 4; ++j)
                    acc[i][j] = __builtin_amdgcn_mfma_f32_16x16x32_bf16(af[i], bfr[j], acc[i][j], 0, 0, 0);
        }
        __syncthreads();
    }
    #pragma unroll
    for (int i = 0; i < 4; ++i){
        #pragma unroll
        for (int r = 0; r < 4; ++r){
            const int s = s0 + wm + i*16 + quad*4 + r;
            const int width = rowWidth(s);
            unsigned short* pr = P + rowOff(s);
            float psum = 0.f;
            if (t0 + wn < width){                    // 64-chunk uniform in/out
                #pragma unroll
                for (int j = 0; j < 4; ++j){
                    const int t = t0 + wn + j*16 + l15;
                    const float e = (t <= s) ? __expf(acc[i][j][r] * scale) : 0.f;
                    pr[t] = f2bfbits(e);
                    psum += e;
                }
                // reduce across the 16 lanes (l15) sharing row s
                #pragma unroll
                for (int off = 8; off > 0; off >>= 1) psum += __shfl_xor(psum, off, 64);
                if (l15 == 0) atomicAdd(&L[s], psum);
            }
        }
    }
}

// ---------- ctx = (P @ V) / l ; A=packed unnormalized P, B=VT[d][tok] ----------
// Natural round-robin mapping: each XCD gets one block per (y,z) row (balanced)
// and a fixed x column (shared 2MB VT panel -> local).
__global__ __launch_bounds__(256)
void pv_mfma(const unsigned short* __restrict__ Pb, const unsigned short* __restrict__ VT,
             unsigned short* __restrict__ Cb, const unsigned short* __restrict__ zpad,
             const float* __restrict__ Lf)
{
    const int s0 = blockIdx.y*128, n0 = blockIdx.x*128;
    const unsigned short* P = Pb + (size_t)blockIdx.z*PPB;
    unsigned short* C       = Cb + (size_t)blockIdx.z*SD;
    const float* L          = Lf + (size_t)blockIdx.z*SS;
    const int bcol = blockIdx.z*SS;
    __shared__ unsigned short As[128*64];
    __shared__ unsigned short Bs[128*64];
    const int tid = threadIdx.x, lane = tid & 63, wave = tid >> 6;
    const int wm = ((wave >> 1) & 1) * 64, wn = (wave & 1) * 64;
    const int quad = lane >> 4, l15 = lane & 15;
    const unsigned short* ga[4]; const unsigned short* gb[4]; int pw[4];
    #pragma unroll
    for (int c = 0; c < 4; ++c){
        const int mr = (wave*4 + c)*8 + (lane >> 3);
        const int gk = ((lane & 7) - mr) & 7;
        const int s = s0 + mr;
        pw[c] = rowWidth(s) - gk*8;                 // valid iff k0 < pw
        ga[c] = P + rowOff(s) + gk*8;
        gb[c] = VT + (size_t)(n0 + mr)*MM + bcol + gk*8;
    }
    f32x4 acc[4][4] = {};
    const int kmax = s0 + 128;
    for (int k0 = 0; k0 < kmax; k0 += 64){
        #pragma unroll
        for (int c = 0; c < 4; ++c){
            const unsigned short* gp = (k0 < pw[c]) ? (ga[c] + k0) : zpad;
            gl_lds(gp, &As[(wave*4+c)*512]);
            gl_lds(gb[c] + k0, &Bs[(wave*4+c)*512]);
        }
        __syncthreads();
        #pragma unroll
        for (int kk = 0; kk < 2; ++kk){
            bf16x8 af[4], bfr[4];
            #pragma unroll
            for (int t = 0; t < 4; ++t){
                const int ra = wm + t*16 + l15, rb = wn + t*16 + l15, gi = kk*4 + quad;
                af[t]  = *(const bf16x8*)&As[ra*64 + (((gi + ra) & 7) << 3)];
                bfr[t] = *(const bf16x8*)&Bs[rb*64 + (((gi + rb) & 7) << 3)];
            }
            #pragma unroll
            for (int i = 0; i < 4; ++i)
                #pragma unroll
                for (int j = 0; j < 4; ++j)
                    acc[i][j] = __builtin_amdgcn_mfma_f32_16x16x32_bf16(af[i], bfr[j], acc[i][j], 0, 0, 0);
        }
        __syncthreads();
    }
    #pragma unroll
    for (int i = 0; i < 4; ++i){
        #pragma unroll
        for (int r = 0; r < 4; ++r){
            const int s = s0 + wm + i*16 + quad*4 + r;
            const float linv = 1.0f / L[s];
            #pragma unroll
            for (int j = 0; j < 4; ++j){
                const int n = n0 + wn + j*16 + l15;
                C[(size_t)s*DD + n] = f2bfbits(acc[i][j][r] * linv);
            }
        }
    }
}

extern "C" void kernel_launch(void* const* d_in, const int* in_sizes, int n_in,
                              void* d_out, int out_size, void* d_ws, size_t ws_size,
                              hipStream_t stream)
{
    (void)in_sizes; (void)n_in; (void)out_size;
    const float* x   = (const float*)d_in[0];
    const float* bq  = (const float*)d_in[2];
    const float* bk  = (const float*)d_in[4];
    const float* bv  = (const float*)d_in[6];
    const float* bo  = (const float*)d_in[8];
    const float* b1  = (const float*)d_in[10];
    const float* b2  = (const float*)d_in[12];
    const float* g1  = (const float*)d_in[13];
    const float* be1 = (const float*)d_in[14];
    const float* g2  = (const float*)d_in[15];
    const float* be2 = (const float*)d_in[16];
    float* outf = (float*)d_out;

    if (ws_size < (size_t)REQ_WS){
        sentinel_kernel<<<dim3((unsigned)(MD/256)), dim3(256), 0, stream>>>(outf, 1.0e9f);
        return;
    }

    unsigned short* wsb = (unsigned short*)d_ws;
    unsigned short* Qw  = wsb;                 // -> ctx
    unsigned short* Kw  = wsb + MD;            // \ -> Hf (fp32 spans K+VT)
    unsigned short* VTw = wsb + 2*MD;          // /
    unsigned short* Pw  = wsb + 3*MD;          // packed P -> mid
    unsigned short* WT  = wsb + WT_OFF;
    unsigned short* ZP  = wsb + ZP_OFF;
    float*          Lf  = (float*)(wsb + LF_OFF);
    float*          Hf  = (float*)Kw;
    unsigned short* CTX = Qw;
    unsigned short* MIDw= Pw;
    unsigned short* LN  = (unsigned short*)d_out;   // LN1/LN2 scratch in d_out

    WPack wp;
    static const int widx[6] = {1,3,5,7,9,11};
    for (int i = 0; i < 6; ++i){
        wp.w[i] = (const float*)d_in[widx[i]];
        wp.o[i] = WT + (size_t)i*DD*DD;
    }
    wp.zp = ZP;
    wp.lf = Lf;
    unsigned short* WqT = wp.o[0]; unsigned short* WkT = wp.o[1];
    unsigned short* WvT = wp.o[2]; unsigned short* WoT = wp.o[3];
    unsigned short* W1T = wp.o[4]; unsigned short* W2T = wp.o[5];

    const dim3 blk(256);
    const float scale = 1.0f / sqrtf((float)SS);
    const dim3 gA(DD/128, MM/128);    // (8,64)

    wtrans<<<dim3(16,16,6), blk, 0, stream>>>(wp);
    ln_f32<<<dim3(MM), blk, 0, stream>>>(x, g1, be1, LN);
    // fused Q + K + VT projections (1536 uniform tiles, one launch)
    proj_fused<<<dim3(1536), blk, 0, stream>>>(LN, WqT, WkT, WvT, bq, bk, bv, Qw, Kw, VTw);
    // attention: fused exp-scores (+row sums, triangular-packed) then PV (/rowsum)
    scores_mfma<<<dim3(544), blk, 0, stream>>>(Qw, Kw, Pw, Lf, scale);
    pv_mfma<<<dim3(DD/128, SS/128, BB), blk, 0, stream>>>(Pw, VTw, CTX, ZP, Lf);
    // h = ctx*WoT^T + bo + x (fp32)
    gemm_mfma<false,true,true,false><<<gA, blk, 0, stream>>>(CTX, WoT, bo, x, nullptr, Hf, DD, DD, DD, DD);
    ln_f32<<<dim3(MM), blk, 0, stream>>>(Hf, g2, be2, LN);
    // mid = relu(LN*W1T^T + b1)
    gemm_mfma<true,false,false,false><<<gA, blk, 0, stream>>>(LN, W1T, b1, nullptr, MIDw, nullptr, DD, DD, DD, DD);
    // out = mid*W2T^T + b2 + h
    gemm_mfma<false,true,true,false><<<gA, blk, 0, stream>>>(MIDw, W2T, b2, Hf, nullptr, outf, DD, DD, DD, DD);
}

// Round 7
// 363.438 us; speedup vs baseline: 1.0866x; 1.0163x over previous
//
#include <hip/hip_runtime.h>
#include <math.h>

#define BB 4
#define SS 2048
#define DD 1024
#define MM (BB*SS)                   // 8192
#define SD ((size_t)SS*DD)
#define MD ((size_t)MM*DD)           // 8,388,608
#define PPB ((size_t)2162688)        // packed P elems per batch

// ws (bf16 elems): Q@0 | K@MD | VT@2MD | P@3MD (4*PPB) | WT (6*DD*DD) | zpad(16) | L (8192 f32)
#define WT_OFF (3*MD + 4*PPB)
#define ZP_OFF (WT_OFF + 6*(size_t)DD*DD)
#define LF_OFF (ZP_OFF + 16)
#define REQ_WS ((LF_OFF + 16384) * 2)

constexpr float LN_EPS = 1e-6f;

typedef __attribute__((ext_vector_type(8))) __bf16 bf16x8;
typedef __attribute__((ext_vector_type(4))) float f32x4;

__device__ __forceinline__ unsigned short f2bfbits(float f){
    unsigned u = __float_as_uint(f);
    u += 0x7FFFu + ((u >> 16) & 1u);   // RNE
    return (unsigned short)(u >> 16);
}
__device__ __forceinline__ int rowWidth(int s){ return ((s >> 6) + 1) << 6; }
__device__ __forceinline__ size_t rowOff(int s){
    int g = s >> 6;
    return (size_t)4096 * (size_t)((g * (g + 1)) >> 1) + (size_t)(s & 63) * (size_t)((g + 1) << 6);
}
// async global->LDS, 16B per lane; LDS dest = wave-uniform base + lane*16
__device__ __forceinline__ void gl_lds(const unsigned short* g, unsigned short* l){
    __builtin_amdgcn_global_load_lds(
        (const __attribute__((address_space(1))) unsigned int*)g,
        (__attribute__((address_space(3))) unsigned int*)l, 16, 0, 0);
}

// XCD-aware bijective block swizzle (T1) — uniform-work launches only.
__device__ __forceinline__ int3 xcd_swz(){
    const int gx = gridDim.x, gy = gridDim.y, gz = gridDim.z;
    const int n = gx * gy * gz;
    int lin = blockIdx.x + gx * (blockIdx.y + gy * blockIdx.z);
    const int cpx = n >> 3;                 // n % 8 == 0 for all swizzled launches
    lin = (lin & 7) * cpx + (lin >> 3);     // bijection: XCD (lin&7) owns chunk
    int3 r;
    r.x = lin % gx; lin /= gx;
    r.y = lin % gy;
    r.z = lin / gy;
    return r;
}

__global__ __launch_bounds__(256)
void sentinel_kernel(float* __restrict__ out, const float val){
    out[(size_t)blockIdx.x * 256 + threadIdx.x] = val;
}

// ---------- prep: fused {weight transpose + zpad/L zero} and {LayerNorm1} ----------
// id < 1536: wtrans tile (6 weights x 16x16 tiles of 64x64). id >= 1536: LN row.
// Independent memory-bound streams -> one launch overlaps them, saves a gap.
struct WPack { const float* w[6]; unsigned short* o[6]; unsigned short* zp; float* lf; };
struct PrepArgs { WPack wp; const float* x; const float* g1; const float* be1;
                  unsigned short* ln; };
__global__ __launch_bounds__(256)
void prep(PrepArgs pa)
{
    const int id = blockIdx.x;
    const int tid = threadIdx.x;
    if (id < 1536){
        __shared__ float Ts[64][65];
        const int z = id >> 8, rem = id & 255;
        const int yy = rem >> 4, xx = rem & 15;
        const float* W = pa.wp.w[z];
        unsigned short* WT = pa.wp.o[z];
        const int r0 = yy*64, c0 = xx*64;
        if (id == 0 && tid < 16) pa.wp.zp[tid] = 0;
        if (id < 16){                       // zero L[8192] f32 (16 blocks x 256 x float2)
            float2 z2 = {0.f, 0.f};
            ((float2*)pa.wp.lf)[id*256 + tid] = z2;
        }
        #pragma unroll
        for (int i = 0; i < 16; ++i){
            int lin = tid + i*256;
            int r = lin >> 6, c = lin & 63;
            Ts[r][c] = W[(size_t)(r0+r)*DD + c0+c];
        }
        __syncthreads();
        #pragma unroll
        for (int i = 0; i < 16; ++i){
            int lin = tid + i*256;
            int r = lin >> 6, c = lin & 63;
            WT[(size_t)(c0+r)*DD + r0+c] = f2bfbits(Ts[c][r]);
        }
    } else {
        __shared__ float red[4];
        const int row = id - 1536;
        float4 xv = ((const float4*)(pa.x + (size_t)row*DD))[tid];
        float v[4] = {xv.x, xv.y, xv.z, xv.w};
        float s = v[0]+v[1]+v[2]+v[3];
        #pragma unroll
        for (int off = 32; off > 0; off >>= 1) s += __shfl_down(s, off, 64);
        if ((tid & 63) == 0) red[tid >> 6] = s;
        __syncthreads();
        const float mean = (red[0]+red[1]+red[2]+red[3]) * (1.0f/DD);
        __syncthreads();
        float q = 0.f;
        #pragma unroll
        for (int i = 0; i < 4; ++i){ float d = v[i]-mean; q += d*d; }
        #pragma unroll
        for (int off = 32; off > 0; off >>= 1) q += __shfl_down(q, off, 64);
        if ((tid & 63) == 0) red[tid >> 6] = q;
        __syncthreads();
        const float var = (red[0]+red[1]+red[2]+red[3]) * (1.0f/(DD-1));
        const float inv = 1.0f/(sqrtf(var) + LN_EPS);
        float4 g4 = ((const float4*)pa.g1)[tid];
        float4 b4 = ((const float4*)pa.be1)[tid];
        ushort4 o;
        o.x = f2bfbits(g4.x*(v[0]-mean)*inv + b4.x);
        o.y = f2bfbits(g4.y*(v[1]-mean)*inv + b4.y);
        o.z = f2bfbits(g4.z*(v[2]-mean)*inv + b4.z);
        o.w = f2bfbits(g4.w*(v[3]-mean)*inv + b4.w);
        ((ushort4*)(pa.ln + (size_t)row*DD))[tid] = o;
    }
}

// ---------- LayerNorm: fp32 in -> bf16 out (standalone, for LN2) ----------
__global__ __launch_bounds__(256)
void ln_f32(const float* __restrict__ x, const float* __restrict__ gamma,
            const float* __restrict__ beta, unsigned short* __restrict__ out)
{
    __shared__ float red[4];
    const int row = blockIdx.x;
    const int tid = threadIdx.x;
    float4 xv = ((const float4*)(x + (size_t)row*DD))[tid];
    float v[4] = {xv.x, xv.y, xv.z, xv.w};
    float s = v[0]+v[1]+v[2]+v[3];
    #pragma unroll
    for (int off = 32; off > 0; off >>= 1) s += __shfl_down(s, off, 64);
    if ((tid & 63) == 0) red[tid >> 6] = s;
    __syncthreads();
    const float mean = (red[0]+red[1]+red[2]+red[3]) * (1.0f/DD);
    __syncthreads();
    float q = 0.f;
    #pragma unroll
    for (int i = 0; i < 4; ++i){ float d = v[i]-mean; q += d*d; }
    #pragma unroll
    for (int off = 32; off > 0; off >>= 1) q += __shfl_down(q, off, 64);
    if ((tid & 63) == 0) red[tid >> 6] = q;
    __syncthreads();
    const float var = (red[0]+red[1]+red[2]+red[3]) * (1.0f/(DD-1));
    const float inv = 1.0f/(sqrtf(var) + LN_EPS);
    float4 g4 = ((const float4*)gamma)[tid];
    float4 b4 = ((const float4*)beta)[tid];
    ushort4 o;
    o.x = f2bfbits(g4.x*(v[0]-mean)*inv + b4.x);
    o.y = f2bfbits(g4.y*(v[1]-mean)*inv + b4.y);
    o.z = f2bfbits(g4.z*(v[2]-mean)*inv + b4.z);
    o.w = f2bfbits(g4.w*(v[3]-mean)*inv + b4.w);
    ((ushort4*)(out + (size_t)row*DD))[tid] = o;
}

// =========== MFMA GEMM core: C[128,128] tile of A[M,K]*B[N,K]^T ===========
// BK=64, 4 waves 2x2, each 64x64. global_load_lds staging, granule-rotated LDS
// (rotation = pre-swizzled global source -> conflict-free ds_read, measured 0).
// (R1-measured-best structure, ~730 TF invariant across R1/R3/R4/R6 variants.)
template<bool RELU, bool RES, bool OUTF, bool BIAS_M>
__device__ __forceinline__ void gemm_core(
    const unsigned short* __restrict__ A, const unsigned short* __restrict__ B,
    const float* __restrict__ bias, const float* __restrict__ resF,
    unsigned short* __restrict__ outB, float* __restrict__ outF,
    const int N, const int K, const int lda, const int ldb,
    const int m0, const int n0,
    unsigned short* As, unsigned short* Bs)
{
    const int tid = threadIdx.x, lane = tid & 63, wave = tid >> 6;
    const int wm = ((wave >> 1) & 1) * 64, wn = (wave & 1) * 64;
    const int quad = lane >> 4, l15 = lane & 15;
    const unsigned short* ga[4]; const unsigned short* gb[4];
    #pragma unroll
    for (int c = 0; c < 4; ++c){
        const int mr = (wave*4 + c)*8 + (lane >> 3);
        const int gk = ((lane & 7) - mr) & 7;
        ga[c] = A + (size_t)(m0 + mr)*lda + gk*8;
        gb[c] = B + (size_t)(n0 + mr)*ldb + gk*8;
    }
    f32x4 acc[4][4] = {};
    for (int k0 = 0; k0 < K; k0 += 64){
        #pragma unroll
        for (int c = 0; c < 4; ++c){
            gl_lds(ga[c] + k0, &As[(wave*4+c)*512]);
            gl_lds(gb[c] + k0, &Bs[(wave*4+c)*512]);
        }
        __syncthreads();
        #pragma unroll
        for (int kk = 0; kk < 2; ++kk){
            bf16x8 af[4], bfr[4];
            #pragma unroll
            for (int t = 0; t < 4; ++t){
                const int ra = wm + t*16 + l15, rb = wn + t*16 + l15, gi = kk*4 + quad;
                af[t]  = *(const bf16x8*)&As[ra*64 + (((gi + ra) & 7) << 3)];
                bfr[t] = *(const bf16x8*)&Bs[rb*64 + (((gi + rb) & 7) << 3)];
            }
            #pragma unroll
            for (int i = 0; i < 4; ++i)
                #pragma unroll
                for (int j = 0; j < 4; ++j)
                    acc[i][j] = __builtin_amdgcn_mfma_f32_16x16x32_bf16(af[i], bfr[j], acc[i][j], 0, 0, 0);
        }
        __syncthreads();
    }
    #pragma unroll
    for (int i = 0; i < 4; ++i){
        #pragma unroll
        for (int r = 0; r < 4; ++r){
            const int m = m0 + wm + i*16 + quad*4 + r;
            const float bm = BIAS_M ? bias[m] : 0.f;
            #pragma unroll
            for (int j = 0; j < 4; ++j){
                const int n = n0 + wn + j*16 + l15;
                float v = acc[i][j][r] + (BIAS_M ? bm : bias[n]);
                if constexpr (RELU) v = fmaxf(v, 0.f);
                if constexpr (RES) v += resF[(size_t)m*N + n];
                if constexpr (OUTF) outF[(size_t)m*N + n] = v;
                else outB[(size_t)m*N + n] = f2bfbits(v);
            }
        }
    }
}

// generic single GEMM
template<bool RELU, bool RES, bool OUTF, bool BIAS_M>
__global__ __launch_bounds__(256)
void gemm_mfma(const unsigned short* __restrict__ A, const unsigned short* __restrict__ B,
               const float* __restrict__ bias, const float* __restrict__ resF,
               unsigned short* __restrict__ outB, float* __restrict__ outF,
               const int N, const int K, const int lda, const int ldb)
{
    __shared__ unsigned short As[128*64];
    __shared__ unsigned short Bs[128*64];
    const int3 b = xcd_swz();
    gemm_core<RELU,RES,OUTF,BIAS_M>(A, B, bias, resF, outB, outF, N, K, lda, ldb,
                                    b.y*128, b.x*128, As, Bs);
}

// ---------- fused Q/K/VT projections: 1536 uniform tiles in ONE launch ----------
__global__ __launch_bounds__(256)
void proj_fused(const unsigned short* __restrict__ LN,
                const unsigned short* __restrict__ WqT, const unsigned short* __restrict__ WkT,
                const unsigned short* __restrict__ WvT,
                const float* __restrict__ bq, const float* __restrict__ bk,
                const float* __restrict__ bv,
                unsigned short* __restrict__ Qw, unsigned short* __restrict__ Kw,
                unsigned short* __restrict__ VTw)
{
    __shared__ unsigned short As[128*64];
    __shared__ unsigned short Bs[128*64];
    const int lin = blockIdx.x;                    // 1536
    const int id = (lin & 7) * 192 + (lin >> 3);   // chunked XCD swizzle
    if (id < 1024){
        const bool isK = (id >= 512);
        const int q = id & 511;
        const int n0 = (q & 7) * 128, m0 = (q >> 3) * 128;   // n over DD, m over MM
        gemm_core<false,false,false,false>(LN, isK ? WkT : WqT, isK ? bk : bq, nullptr,
                                           isK ? Kw : Qw, nullptr, DD, DD, DD, DD,
                                           m0, n0, As, Bs);
    } else {
        const int q = id - 1024;
        const int n0 = (q & 63) * 128, m0 = (q >> 6) * 128;  // n over MM, m over DD
        gemm_core<false,false,false,true>(WvT, LN, bv, nullptr, VTw, nullptr,
                                          MM, DD, DD, DD, m0, n0, As, Bs);
    }
}

// ---------- scores: packed P = exp(Q*K^T * scale), causal, UNNORMALIZED ----------
// Triangular-packed launch: exactly 544 active tiles, uniform cost ->
// chunked XCD swizzle balanced + local. Row sums -> atomicAdd L.
__global__ __launch_bounds__(256)
void scores_mfma(const unsigned short* __restrict__ Qb, const unsigned short* __restrict__ Kb,
                 unsigned short* __restrict__ Pb, float* __restrict__ Lf, const float scale)
{
    const int lin = blockIdx.x;                    // 544 = 4 * 136
    const int id = (lin & 7) * 68 + (lin >> 3);    // chunked XCD swizzle
    const int z = id / 136;
    const int idx = id - z * 136;
    int y = (int)((sqrtf(8.f * (float)idx + 1.f) - 1.f) * 0.5f);
    while ((y + 1) * (y + 2) / 2 <= idx) ++y;      // guard float error
    while (y * (y + 1) / 2 > idx) --y;
    const int x = idx - y * (y + 1) / 2;           // x <= y
    const int s0 = y * 128, t0 = x * 128;

    const unsigned short* Q  = Qb + (size_t)z*SD;
    const unsigned short* Km = Kb + (size_t)z*SD;
    unsigned short* P        = Pb + (size_t)z*PPB;
    float* L                 = Lf + (size_t)z*SS;
    __shared__ unsigned short As[128*64];
    __shared__ unsigned short Bs[128*64];
    const int tid = threadIdx.x, lane = tid & 63, wave = tid >> 6;
    const int wm = ((wave >> 1) & 1) * 64, wn = (wave & 1) * 64;
    const int quad = lane >> 4, l15 = lane & 15;
    const unsigned short* ga[4]; const unsigned short* gb[4];
    #pragma unroll
    for (int c = 0; c < 4; ++c){
        const int mr = (wave*4 + c)*8 + (lane >> 3);
        const int gk = ((lane & 7) - mr) & 7;
        ga[c] = Q  + (size_t)(s0 + mr)*DD + gk*8;
        gb[c] = Km + (size_t)(t0 + mr)*DD + gk*8;
    }
    f32x4 acc[4][4] = {};
    for (int k0 = 0; k0 < DD; k0 += 64){
        #pragma unroll
        for (int c = 0; c < 4; ++c){
            gl_lds(ga[c] + k0, &As[(wave*4+c)*512]);
            gl_lds(gb[c] + k0, &Bs[(wave*4+c)*512]);
        }
        __syncthreads();
        #pragma unroll
        for (int kk = 0; kk < 2; ++kk){
            bf16x8 af[4], bfr[4];
            #pragma unroll
            for (int t = 0; t < 4; ++t){
                const int ra = wm + t*16 + l15, rb = wn + t*16 + l15, gi = kk*4 + quad;
                af[t]  = *(const bf16x8*)&As[ra*64 + (((gi + ra) & 7) << 3)];
                bfr[t] = *(const bf16x8*)&Bs[rb*64 + (((gi + rb) & 7) << 3)];
            }
            #pragma unroll
            for (int i = 0; i < 4; ++i)
                #pragma unroll
                for (int j = 0; j < 4; ++j)
                    acc[i][j] = __builtin_amdgcn_mfma_f32_16x16x32_bf16(af[i], bfr[j], acc[i][j], 0, 0, 0);
        }
        __syncthreads();
    }
    #pragma unroll
    for (int i = 0; i < 4; ++i){
        #pragma unroll
        for (int r = 0; r < 4; ++r){
            const int s = s0 + wm + i*16 + quad*4 + r;
            const int width = rowWidth(s);
            unsigned short* pr = P + rowOff(s);
            float psum = 0.f;
            if (t0 + wn < width){                    // 64-chunk uniform in/out
                #pragma unroll
                for (int j = 0; j < 4; ++j){
                    const int t = t0 + wn + j*16 + l15;
                    const float e = (t <= s) ? __expf(acc[i][j][r] * scale) : 0.f;
                    pr[t] = f2bfbits(e);
                    psum += e;
                }
                #pragma unroll
                for (int off = 8; off > 0; off >>= 1) psum += __shfl_xor(psum, off, 64);
                if (l15 == 0) atomicAdd(&L[s], psum);
            }
        }
    }
}

// ---------- ctx = (P @ V) / l ; A=packed unnormalized P, B=VT[d][tok] ----------
// Causal-balance remap: y' = (z>=2) ? 15-y : y. Co-resident block pairs
// (lin, lin+256) then have complementary y -> every CU gets 36 combined
// K-steps instead of worst-case 64 (kernel was tail-bound by y=15 stragglers).
__global__ __launch_bounds__(256)
void pv_mfma(const unsigned short* __restrict__ Pb, const unsigned short* __restrict__ VT,
             unsigned short* __restrict__ Cb, const unsigned short* __restrict__ zpad,
             const float* __restrict__ Lf)
{
    const int yr = blockIdx.y;
    const int y  = (blockIdx.z >= 2) ? (15 - yr) : yr;
    const int s0 = y*128, n0 = blockIdx.x*128;
    const unsigned short* P = Pb + (size_t)blockIdx.z*PPB;
    unsigned short* C       = Cb + (size_t)blockIdx.z*SD;
    const float* L          = Lf + (size_t)blockIdx.z*SS;
    const int bcol = blockIdx.z*SS;
    __shared__ unsigned short As[128*64];
    __shared__ unsigned short Bs[128*64];
    const int tid = threadIdx.x, lane = tid & 63, wave = tid >> 6;
    const int wm = ((wave >> 1) & 1) * 64, wn = (wave & 1) * 64;
    const int quad = lane >> 4, l15 = lane & 15;
    const unsigned short* ga[4]; const unsigned short* gb[4]; int pw[4];
    #pragma unroll
    for (int c = 0; c < 4; ++c){
        const int mr = (wave*4 + c)*8 + (lane >> 3);
        const int gk = ((lane & 7) - mr) & 7;
        const int s = s0 + mr;
        pw[c] = rowWidth(s) - gk*8;                 // valid iff k0 < pw
        ga[c] = P + rowOff(s) + gk*8;
        gb[c] = VT + (size_t)(n0 + mr)*MM + bcol + gk*8;
    }
    f32x4 acc[4][4] = {};
    const int kmax = s0 + 128;
    for (int k0 = 0; k0 < kmax; k0 += 64){
        #pragma unroll
        for (int c = 0; c < 4; ++c){
            const unsigned short* gp = (k0 < pw[c]) ? (ga[c] + k0) : zpad;
            gl_lds(gp, &As[(wave*4+c)*512]);
            gl_lds(gb[c] + k0, &Bs[(wave*4+c)*512]);
        }
        __syncthreads();
        #pragma unroll
        for (int kk = 0; kk < 2; ++kk){
            bf16x8 af[4], bfr[4];
            #pragma unroll
            for (int t = 0; t < 4; ++t){
                const int ra = wm + t*16 + l15, rb = wn + t*16 + l15, gi = kk*4 + quad;
                af[t]  = *(const bf16x8*)&As[ra*64 + (((gi + ra) & 7) << 3)];
                bfr[t] = *(const bf16x8*)&Bs[rb*64 + (((gi + rb) & 7) << 3)];
            }
            #pragma unroll
            for (int i = 0; i < 4; ++i)
                #pragma unroll
                for (int j = 0; j < 4; ++j)
                    acc[i][j] = __builtin_amdgcn_mfma_f32_16x16x32_bf16(af[i], bfr[j], acc[i][j], 0, 0, 0);
        }
        __syncthreads();
    }
    #pragma unroll
    for (int i = 0; i < 4; ++i){
        #pragma unroll
        for (int r = 0; r < 4; ++r){
            const int s = s0 + wm + i*16 + quad*4 + r;
            const float linv = 1.0f / L[s];
            #pragma unroll
            for (int j = 0; j < 4; ++j){
                const int n = n0 + wn + j*16 + l15;
                C[(size_t)s*DD + n] = f2bfbits(acc[i][j][r] * linv);
            }
        }
    }
}

extern "C" void kernel_launch(void* const* d_in, const int* in_sizes, int n_in,
                              void* d_out, int out_size, void* d_ws, size_t ws_size,
                              hipStream_t stream)
{
    (void)in_sizes; (void)n_in; (void)out_size;
    const float* x   = (const float*)d_in[0];
    const float* bq  = (const float*)d_in[2];
    const float* bk  = (const float*)d_in[4];
    const float* bv  = (const float*)d_in[6];
    const float* bo  = (const float*)d_in[8];
    const float* b1  = (const float*)d_in[10];
    const float* b2  = (const float*)d_in[12];
    const float* g1  = (const float*)d_in[13];
    const float* be1 = (const float*)d_in[14];
    const float* g2  = (const float*)d_in[15];
    const float* be2 = (const float*)d_in[16];
    float* outf = (float*)d_out;

    if (ws_size < (size_t)REQ_WS){
        sentinel_kernel<<<dim3((unsigned)(MD/256)), dim3(256), 0, stream>>>(outf, 1.0e9f);
        return;
    }

    unsigned short* wsb = (unsigned short*)d_ws;
    unsigned short* Qw  = wsb;                 // -> ctx
    unsigned short* Kw  = wsb + MD;            // \ -> Hf (fp32 spans K+VT)
    unsigned short* VTw = wsb + 2*MD;          // /
    unsigned short* Pw  = wsb + 3*MD;          // packed P -> mid
    unsigned short* WT  = wsb + WT_OFF;
    unsigned short* ZP  = wsb + ZP_OFF;
    float*          Lf  = (float*)(wsb + LF_OFF);
    float*          Hf  = (float*)Kw;
    unsigned short* CTX = Qw;
    unsigned short* MIDw= Pw;
    unsigned short* LN  = (unsigned short*)d_out;   // LN1/LN2 scratch in d_out

    PrepArgs pa;
    static const int widx[6] = {1,3,5,7,9,11};
    for (int i = 0; i < 6; ++i){
        pa.wp.w[i] = (const float*)d_in[widx[i]];
        pa.wp.o[i] = WT + (size_t)i*DD*DD;
    }
    pa.wp.zp = ZP;
    pa.wp.lf = Lf;
    pa.x = x; pa.g1 = g1; pa.be1 = be1; pa.ln = LN;
    unsigned short* WqT = pa.wp.o[0]; unsigned short* WkT = pa.wp.o[1];
    unsigned short* WvT = pa.wp.o[2]; unsigned short* WoT = pa.wp.o[3];
    unsigned short* W1T = pa.wp.o[4]; unsigned short* W2T = pa.wp.o[5];

    const dim3 blk(256);
    const float scale = 1.0f / sqrtf((float)SS);
    const dim3 gA(DD/128, MM/128);    // (8,64)

    // fused wtrans + LN1 (independent streams, one launch)
    prep<<<dim3(1536 + MM), blk, 0, stream>>>(pa);
    // fused Q + K + VT projections (1536 uniform tiles, one launch)
    proj_fused<<<dim3(1536), blk, 0, stream>>>(LN, WqT, WkT, WvT, bq, bk, bv, Qw, Kw, VTw);
    // attention: fused exp-scores (+row sums, triangular-packed) then PV (/rowsum)
    scores_mfma<<<dim3(544), blk, 0, stream>>>(Qw, Kw, Pw, Lf, scale);
    pv_mfma<<<dim3(DD/128, SS/128, BB), blk, 0, stream>>>(Pw, VTw, CTX, ZP, Lf);
    // h = ctx*WoT^T + bo + x (fp32)
    gemm_mfma<false,true,true,false><<<gA, blk, 0, stream>>>(CTX, WoT, bo, x, nullptr, Hf, DD, DD, DD, DD);
    ln_f32<<<dim3(MM), blk, 0, stream>>>(Hf, g2, be2, LN);
    // mid = relu(LN*W1T^T + b1)
    gemm_mfma<true,false,false,false><<<gA, blk, 0, stream>>>(LN, W1T, b1, nullptr, MIDw, nullptr, DD, DD, DD, DD);
    // out = mid*W2T^T + b2 + h
    gemm_mfma<false,true,true,false><<<gA, blk, 0, stream>>>(MIDw, W2T, b2, Hf, nullptr, outf, DD, DD, DD, DD);
}

// Round 8
// 346.398 us; speedup vs baseline: 1.1400x; 1.0492x over previous
//
#include <hip/hip_runtime.h>
#include <math.h>

#define BB 4
#define SS 2048
#define DD 1024
#define MM (BB*SS)                   // 8192
#define SD ((size_t)SS*DD)
#define MD ((size_t)MM*DD)           // 8,388,608
#define PPB ((size_t)2162688)        // packed P elems per batch

// ws (bf16 elems): Q@0 | K@MD | VT@2MD | P@3MD (4*PPB) | WT (6*DD*DD) | zpad(16) | L (8192 f32)
#define WT_OFF (3*MD + 4*PPB)
#define ZP_OFF (WT_OFF + 6*(size_t)DD*DD)
#define LF_OFF (ZP_OFF + 16)
#define REQ_WS ((LF_OFF + 16384) * 2)

constexpr float LN_EPS = 1e-6f;

typedef __attribute__((ext_vector_type(8))) __bf16 bf16x8;
typedef __attribute__((ext_vector_type(4))) float f32x4;

__device__ __forceinline__ unsigned short f2bfbits(float f){
    unsigned u = __float_as_uint(f);
    u += 0x7FFFu + ((u >> 16) & 1u);   // RNE
    return (unsigned short)(u >> 16);
}
__device__ __forceinline__ int rowWidth(int s){ return ((s >> 6) + 1) << 6; }
__device__ __forceinline__ size_t rowOff(int s){
    int g = s >> 6;
    return (size_t)4096 * (size_t)((g * (g + 1)) >> 1) + (size_t)(s & 63) * (size_t)((g + 1) << 6);
}
// async global->LDS, 16B per lane; LDS dest = wave-uniform base + lane*16
__device__ __forceinline__ void gl_lds(const unsigned short* g, unsigned short* l){
    __builtin_amdgcn_global_load_lds(
        (const __attribute__((address_space(1))) unsigned int*)g,
        (__attribute__((address_space(3))) unsigned int*)l, 16, 0, 0);
}

// XCD-aware bijective block swizzle (T1) — uniform-work launches only.
__device__ __forceinline__ int3 xcd_swz(){
    const int gx = gridDim.x, gy = gridDim.y, gz = gridDim.z;
    const int n = gx * gy * gz;
    int lin = blockIdx.x + gx * (blockIdx.y + gy * blockIdx.z);
    const int cpx = n >> 3;                 // n % 8 == 0 for all swizzled launches
    lin = (lin & 7) * cpx + (lin >> 3);     // bijection: XCD (lin&7) owns chunk
    int3 r;
    r.x = lin % gx; lin /= gx;
    r.y = lin % gy;
    r.z = lin / gy;
    return r;
}

__global__ __launch_bounds__(256)
void sentinel_kernel(float* __restrict__ out, const float val){
    out[(size_t)blockIdx.x * 256 + threadIdx.x] = val;
}

// ---------- prep: fused {weight transpose + zpad/L zero} and {LayerNorm1} ----------
struct WPack { const float* w[6]; unsigned short* o[6]; unsigned short* zp; float* lf; };
struct PrepArgs { WPack wp; const float* x; const float* g1; const float* be1;
                  unsigned short* ln; };
__global__ __launch_bounds__(256)
void prep(PrepArgs pa)
{
    const int id = blockIdx.x;
    const int tid = threadIdx.x;
    if (id < 1536){
        __shared__ float Ts[64][65];
        const int z = id >> 8, rem = id & 255;
        const int yy = rem >> 4, xx = rem & 15;
        const float* W = pa.wp.w[z];
        unsigned short* WT = pa.wp.o[z];
        const int r0 = yy*64, c0 = xx*64;
        if (id == 0 && tid < 16) pa.wp.zp[tid] = 0;
        if (id < 16){                       // zero L[8192] f32
            float2 z2 = {0.f, 0.f};
            ((float2*)pa.wp.lf)[id*256 + tid] = z2;
        }
        #pragma unroll
        for (int i = 0; i < 16; ++i){
            int lin = tid + i*256;
            int r = lin >> 6, c = lin & 63;
            Ts[r][c] = W[(size_t)(r0+r)*DD + c0+c];
        }
        __syncthreads();
        #pragma unroll
        for (int i = 0; i < 16; ++i){
            int lin = tid + i*256;
            int r = lin >> 6, c = lin & 63;
            WT[(size_t)(c0+r)*DD + r0+c] = f2bfbits(Ts[c][r]);
        }
    } else {
        __shared__ float red[4];
        const int row = id - 1536;
        float4 xv = ((const float4*)(pa.x + (size_t)row*DD))[tid];
        float v[4] = {xv.x, xv.y, xv.z, xv.w};
        float s = v[0]+v[1]+v[2]+v[3];
        #pragma unroll
        for (int off = 32; off > 0; off >>= 1) s += __shfl_down(s, off, 64);
        if ((tid & 63) == 0) red[tid >> 6] = s;
        __syncthreads();
        const float mean = (red[0]+red[1]+red[2]+red[3]) * (1.0f/DD);
        __syncthreads();
        float q = 0.f;
        #pragma unroll
        for (int i = 0; i < 4; ++i){ float d = v[i]-mean; q += d*d; }
        #pragma unroll
        for (int off = 32; off > 0; off >>= 1) q += __shfl_down(q, off, 64);
        if ((tid & 63) == 0) red[tid >> 6] = q;
        __syncthreads();
        const float var = (red[0]+red[1]+red[2]+red[3]) * (1.0f/(DD-1));
        const float inv = 1.0f/(sqrtf(var) + LN_EPS);
        float4 g4 = ((const float4*)pa.g1)[tid];
        float4 b4 = ((const float4*)pa.be1)[tid];
        ushort4 o;
        o.x = f2bfbits(g4.x*(v[0]-mean)*inv + b4.x);
        o.y = f2bfbits(g4.y*(v[1]-mean)*inv + b4.y);
        o.z = f2bfbits(g4.z*(v[2]-mean)*inv + b4.z);
        o.w = f2bfbits(g4.w*(v[3]-mean)*inv + b4.w);
        ((ushort4*)(pa.ln + (size_t)row*DD))[tid] = o;
    }
}

// ---------- LayerNorm: fp32 in -> bf16 out (standalone, for LN2) ----------
__global__ __launch_bounds__(256)
void ln_f32(const float* __restrict__ x, const float* __restrict__ gamma,
            const float* __restrict__ beta, unsigned short* __restrict__ out)
{
    __shared__ float red[4];
    const int row = blockIdx.x;
    const int tid = threadIdx.x;
    float4 xv = ((const float4*)(x + (size_t)row*DD))[tid];
    float v[4] = {xv.x, xv.y, xv.z, xv.w};
    float s = v[0]+v[1]+v[2]+v[3];
    #pragma unroll
    for (int off = 32; off > 0; off >>= 1) s += __shfl_down(s, off, 64);
    if ((tid & 63) == 0) red[tid >> 6] = s;
    __syncthreads();
    const float mean = (red[0]+red[1]+red[2]+red[3]) * (1.0f/DD);
    __syncthreads();
    float q = 0.f;
    #pragma unroll
    for (int i = 0; i < 4; ++i){ float d = v[i]-mean; q += d*d; }
    #pragma unroll
    for (int off = 32; off > 0; off >>= 1) q += __shfl_down(q, off, 64);
    if ((tid & 63) == 0) red[tid >> 6] = q;
    __syncthreads();
    const float var = (red[0]+red[1]+red[2]+red[3]) * (1.0f/(DD-1));
    const float inv = 1.0f/(sqrtf(var) + LN_EPS);
    float4 g4 = ((const float4*)gamma)[tid];
    float4 b4 = ((const float4*)beta)[tid];
    ushort4 o;
    o.x = f2bfbits(g4.x*(v[0]-mean)*inv + b4.x);
    o.y = f2bfbits(g4.y*(v[1]-mean)*inv + b4.y);
    o.z = f2bfbits(g4.z*(v[2]-mean)*inv + b4.z);
    o.w = f2bfbits(g4.w*(v[3]-mean)*inv + b4.w);
    ((ushort4*)(out + (size_t)row*DD))[tid] = o;
}

// =========== double-buffered MFMA main loop (iso-occupancy pipelining) ===========
// 128x128 tile, BK=64, 4 waves 2x2. TWO static buffer pairs (64 KB total ->
// still 2 blocks/CU, unlike R3/R4's 96-144 KB which dropped to 1). Per K-pair:
//   stage(buf1,t+1); vmcnt(8); bar; compute(buf0); bar;
//   stage(buf0,t+2); vmcnt(8); bar; compute(buf1); bar;
// Counted vmcnt(8) = the 8 loads just issued stay in flight; each tile's loads
// get a full compute phase to land instead of zero (R1 drained at each sync).
// NT must be even (all call sites: 16 or 2y+2).
template<bool PACKED>
__device__ __forceinline__ void mfma_db(
    const unsigned short* const ga[4], const unsigned short* const gb[4],
    const int* pw, const unsigned short* zpad, const int NT,
    f32x4 acc[4][4], const int wave, const int lane,
    unsigned short (&As0)[8192], unsigned short (&Bs0)[8192],
    unsigned short (&As1)[8192], unsigned short (&Bs1)[8192])
{
    const int quad = lane >> 4, l15 = lane & 15;
    const int wm = ((wave >> 1) & 1) * 64, wn = (wave & 1) * 64;

    auto stage = [&](unsigned short (&Ab)[8192], unsigned short (&Bb)[8192], const int koff){
        #pragma unroll
        for (int c = 0; c < 4; ++c){
            const unsigned short* gp = ga[c] + koff;
            if constexpr (PACKED) { if (koff >= pw[c]) gp = zpad; }
            gl_lds(gp, &Ab[(wave*4+c)*512]);
            gl_lds(gb[c] + koff, &Bb[(wave*4+c)*512]);
        }
    };
    auto compute = [&](unsigned short (&Ab)[8192], unsigned short (&Bb)[8192]){
        #pragma unroll
        for (int kk = 0; kk < 2; ++kk){
            bf16x8 af[4], bfr[4];
            #pragma unroll
            for (int t = 0; t < 4; ++t){
                const int ra = wm + t*16 + l15, rb = wn + t*16 + l15, gi = kk*4 + quad;
                af[t]  = *(const bf16x8*)&Ab[ra*64 + (((gi + ra) & 7) << 3)];
                bfr[t] = *(const bf16x8*)&Bb[rb*64 + (((gi + rb) & 7) << 3)];
            }
            #pragma unroll
            for (int i = 0; i < 4; ++i)
                #pragma unroll
                for (int j = 0; j < 4; ++j)
                    acc[i][j] = __builtin_amdgcn_mfma_f32_16x16x32_bf16(af[i], bfr[j], acc[i][j], 0, 0, 0);
        }
    };

    stage(As0, Bs0, 0);
    const int half = NT >> 1;
    for (int i = 0; i < half; ++i){
        // readers of As1/Bs1 drained at the closing barrier of iter i-1
        stage(As1, Bs1, (2*i + 1) << 6);
        asm volatile("s_waitcnt vmcnt(8)" ::: "memory");   // buf0 landed; buf1 in flight
        __builtin_amdgcn_s_barrier();
        __builtin_amdgcn_sched_barrier(0);
        compute(As0, Bs0);
        __builtin_amdgcn_s_barrier();                      // buf0 readers drained
        if (i + 1 < half){
            stage(As0, Bs0, (2*i + 2) << 6);
            asm volatile("s_waitcnt vmcnt(8)" ::: "memory");   // buf1 landed
        } else {
            asm volatile("s_waitcnt vmcnt(0)" ::: "memory");   // tail drain
        }
        __builtin_amdgcn_s_barrier();
        __builtin_amdgcn_sched_barrier(0);
        compute(As1, Bs1);
        __builtin_amdgcn_s_barrier();                      // buf1 readers drained
    }
}

__device__ __forceinline__ void mk_chunks(const unsigned short* base, size_t ld, int r0,
                                          int wave, int lane, const unsigned short* g[4]){
    #pragma unroll
    for (int c = 0; c < 4; ++c){
        const int mr = (wave*4 + c)*8 + (lane >> 3);
        const int gk = ((lane & 7) - mr) & 7;
        g[c] = base + (size_t)(r0 + mr)*ld + gk*8;
    }
}

#define DECL_DB \
    __shared__ unsigned short As0[8192]; \
    __shared__ unsigned short Bs0[8192]; \
    __shared__ unsigned short As1[8192]; \
    __shared__ unsigned short Bs1[8192];

// =========== GEMM core wrapper: C[128,128] tile of A[M,K]*B[N,K]^T ===========
template<bool RELU, bool RES, bool OUTF, bool BIAS_M>
__device__ __forceinline__ void gemm_core(
    const unsigned short* __restrict__ A, const unsigned short* __restrict__ B,
    const float* __restrict__ bias, const float* __restrict__ resF,
    unsigned short* __restrict__ outB, float* __restrict__ outF,
    const int N, const int K, const int lda, const int ldb,
    const int m0, const int n0,
    unsigned short (&As0)[8192], unsigned short (&Bs0)[8192],
    unsigned short (&As1)[8192], unsigned short (&Bs1)[8192])
{
    const int tid = threadIdx.x, lane = tid & 63, wave = tid >> 6;
    const int wm = ((wave >> 1) & 1) * 64, wn = (wave & 1) * 64;
    const int quad = lane >> 4, l15 = lane & 15;
    const unsigned short* ga[4]; const unsigned short* gb[4];
    mk_chunks(A, lda, m0, wave, lane, ga);
    mk_chunks(B, ldb, n0, wave, lane, gb);
    f32x4 acc[4][4] = {};
    mfma_db<false>(ga, gb, nullptr, nullptr, K >> 6, acc, wave, lane, As0, Bs0, As1, Bs1);
    #pragma unroll
    for (int i = 0; i < 4; ++i){
        #pragma unroll
        for (int r = 0; r < 4; ++r){
            const int m = m0 + wm + i*16 + quad*4 + r;
            const float bm = BIAS_M ? bias[m] : 0.f;
            #pragma unroll
            for (int j = 0; j < 4; ++j){
                const int n = n0 + wn + j*16 + l15;
                float v = acc[i][j][r] + (BIAS_M ? bm : bias[n]);
                if constexpr (RELU) v = fmaxf(v, 0.f);
                if constexpr (RES) v += resF[(size_t)m*N + n];
                if constexpr (OUTF) outF[(size_t)m*N + n] = v;
                else outB[(size_t)m*N + n] = f2bfbits(v);
            }
        }
    }
}

// generic single GEMM
template<bool RELU, bool RES, bool OUTF, bool BIAS_M>
__global__ __launch_bounds__(256)
void gemm_mfma(const unsigned short* __restrict__ A, const unsigned short* __restrict__ B,
               const float* __restrict__ bias, const float* __restrict__ resF,
               unsigned short* __restrict__ outB, float* __restrict__ outF,
               const int N, const int K, const int lda, const int ldb)
{
    DECL_DB
    const int3 b = xcd_swz();
    gemm_core<RELU,RES,OUTF,BIAS_M>(A, B, bias, resF, outB, outF, N, K, lda, ldb,
                                    b.y*128, b.x*128, As0, Bs0, As1, Bs1);
}

// ---------- fused Q/K/VT projections: 1536 uniform tiles in ONE launch ----------
__global__ __launch_bounds__(256)
void proj_fused(const unsigned short* __restrict__ LN,
                const unsigned short* __restrict__ WqT, const unsigned short* __restrict__ WkT,
                const unsigned short* __restrict__ WvT,
                const float* __restrict__ bq, const float* __restrict__ bk,
                const float* __restrict__ bv,
                unsigned short* __restrict__ Qw, unsigned short* __restrict__ Kw,
                unsigned short* __restrict__ VTw)
{
    DECL_DB
    const int lin = blockIdx.x;                    // 1536
    const int id = (lin & 7) * 192 + (lin >> 3);   // chunked XCD swizzle
    if (id < 1024){
        const bool isK = (id >= 512);
        const int q = id & 511;
        const int n0 = (q & 7) * 128, m0 = (q >> 3) * 128;   // n over DD, m over MM
        gemm_core<false,false,false,false>(LN, isK ? WkT : WqT, isK ? bk : bq, nullptr,
                                           isK ? Kw : Qw, nullptr, DD, DD, DD, DD,
                                           m0, n0, As0, Bs0, As1, Bs1);
    } else {
        const int q = id - 1024;
        const int n0 = (q & 63) * 128, m0 = (q >> 6) * 128;  // n over MM, m over DD
        gemm_core<false,false,false,true>(WvT, LN, bv, nullptr, VTw, nullptr,
                                          MM, DD, DD, DD, m0, n0, As0, Bs0, As1, Bs1);
    }
}

// ---------- scores: packed P = exp(Q*K^T * scale), causal, UNNORMALIZED ----------
__global__ __launch_bounds__(256)
void scores_mfma(const unsigned short* __restrict__ Qb, const unsigned short* __restrict__ Kb,
                 unsigned short* __restrict__ Pb, float* __restrict__ Lf, const float scale)
{
    const int lin = blockIdx.x;                    // 544 = 4 * 136
    const int id = (lin & 7) * 68 + (lin >> 3);    // chunked XCD swizzle
    const int z = id / 136;
    const int idx = id - z * 136;
    int y = (int)((sqrtf(8.f * (float)idx + 1.f) - 1.f) * 0.5f);
    while ((y + 1) * (y + 2) / 2 <= idx) ++y;      // guard float error
    while (y * (y + 1) / 2 > idx) --y;
    const int x = idx - y * (y + 1) / 2;           // x <= y
    const int s0 = y * 128, t0 = x * 128;

    const unsigned short* Q  = Qb + (size_t)z*SD;
    const unsigned short* Km = Kb + (size_t)z*SD;
    unsigned short* P        = Pb + (size_t)z*PPB;
    float* L                 = Lf + (size_t)z*SS;
    DECL_DB
    const int tid = threadIdx.x, lane = tid & 63, wave = tid >> 6;
    const int wm = ((wave >> 1) & 1) * 64, wn = (wave & 1) * 64;
    const int quad = lane >> 4, l15 = lane & 15;
    const unsigned short* ga[4]; const unsigned short* gb[4];
    mk_chunks(Q,  DD, s0, wave, lane, ga);
    mk_chunks(Km, DD, t0, wave, lane, gb);
    f32x4 acc[4][4] = {};
    mfma_db<false>(ga, gb, nullptr, nullptr, DD >> 6, acc, wave, lane, As0, Bs0, As1, Bs1);

    #pragma unroll
    for (int i = 0; i < 4; ++i){
        #pragma unroll
        for (int r = 0; r < 4; ++r){
            const int s = s0 + wm + i*16 + quad*4 + r;
            const int width = rowWidth(s);
            unsigned short* pr = P + rowOff(s);
            float psum = 0.f;
            if (t0 + wn < width){                    // 64-chunk uniform in/out
                #pragma unroll
                for (int j = 0; j < 4; ++j){
                    const int t = t0 + wn + j*16 + l15;
                    const float e = (t <= s) ? __expf(acc[i][j][r] * scale) : 0.f;
                    pr[t] = f2bfbits(e);
                    psum += e;
                }
                #pragma unroll
                for (int off = 8; off > 0; off >>= 1) psum += __shfl_xor(psum, off, 64);
                if (l15 == 0) atomicAdd(&L[s], psum);
            }
        }
    }
}

// ---------- ctx = (P @ V) / l ; A=packed unnormalized P, B=VT[d][tok] ----------
// Causal-balance remap: y' = (z>=2) ? 15-y : y (complementary co-resident pairs).
__global__ __launch_bounds__(256)
void pv_mfma(const unsigned short* __restrict__ Pb, const unsigned short* __restrict__ VT,
             unsigned short* __restrict__ Cb, const unsigned short* __restrict__ zpad,
             const float* __restrict__ Lf)
{
    const int yr = blockIdx.y;
    const int y  = (blockIdx.z >= 2) ? (15 - yr) : yr;
    const int s0 = y*128, n0 = blockIdx.x*128;
    const unsigned short* P = Pb + (size_t)blockIdx.z*PPB;
    unsigned short* C       = Cb + (size_t)blockIdx.z*SD;
    const float* L          = Lf + (size_t)blockIdx.z*SS;
    const int bcol = blockIdx.z*SS;
    DECL_DB
    const int tid = threadIdx.x, lane = tid & 63, wave = tid >> 6;
    const int wm = ((wave >> 1) & 1) * 64, wn = (wave & 1) * 64;
    const int quad = lane >> 4, l15 = lane & 15;
    const unsigned short* ga[4]; const unsigned short* gb[4]; int pw[4];
    #pragma unroll
    for (int c = 0; c < 4; ++c){
        const int mr = (wave*4 + c)*8 + (lane >> 3);
        const int gk = ((lane & 7) - mr) & 7;
        const int s = s0 + mr;
        pw[c] = rowWidth(s) - gk*8;                 // chunk valid iff koff < pw
        ga[c] = P + rowOff(s) + gk*8;
    }
    mk_chunks(VT + bcol, MM, n0, wave, lane, gb);
    f32x4 acc[4][4] = {};
    const int NT = (s0 >> 6) + 2;                   // 2y+2, even
    mfma_db<true>(ga, gb, pw, zpad, NT, acc, wave, lane, As0, Bs0, As1, Bs1);

    #pragma unroll
    for (int i = 0; i < 4; ++i){
        #pragma unroll
        for (int r = 0; r < 4; ++r){
            const int s = s0 + wm + i*16 + quad*4 + r;
            const float linv = 1.0f / L[s];
            #pragma unroll
            for (int j = 0; j < 4; ++j){
                const int n = n0 + wn + j*16 + l15;
                C[(size_t)s*DD + n] = f2bfbits(acc[i][j][r] * linv);
            }
        }
    }
}

extern "C" void kernel_launch(void* const* d_in, const int* in_sizes, int n_in,
                              void* d_out, int out_size, void* d_ws, size_t ws_size,
                              hipStream_t stream)
{
    (void)in_sizes; (void)n_in; (void)out_size;
    const float* x   = (const float*)d_in[0];
    const float* bq  = (const float*)d_in[2];
    const float* bk  = (const float*)d_in[4];
    const float* bv  = (const float*)d_in[6];
    const float* bo  = (const float*)d_in[8];
    const float* b1  = (const float*)d_in[10];
    const float* b2  = (const float*)d_in[12];
    const float* g1  = (const float*)d_in[13];
    const float* be1 = (const float*)d_in[14];
    const float* g2  = (const float*)d_in[15];
    const float* be2 = (const float*)d_in[16];
    float* outf = (float*)d_out;

    if (ws_size < (size_t)REQ_WS){
        sentinel_kernel<<<dim3((unsigned)(MD/256)), dim3(256), 0, stream>>>(outf, 1.0e9f);
        return;
    }

    unsigned short* wsb = (unsigned short*)d_ws;
    unsigned short* Qw  = wsb;                 // -> ctx
    unsigned short* Kw  = wsb + MD;            // \ -> Hf (fp32 spans K+VT)
    unsigned short* VTw = wsb + 2*MD;          // /
    unsigned short* Pw  = wsb + 3*MD;          // packed P -> mid
    unsigned short* WT  = wsb + WT_OFF;
    unsigned short* ZP  = wsb + ZP_OFF;
    float*          Lf  = (float*)(wsb + LF_OFF);
    float*          Hf  = (float*)Kw;
    unsigned short* CTX = Qw;
    unsigned short* MIDw= Pw;
    unsigned short* LN  = (unsigned short*)d_out;   // LN1/LN2 scratch in d_out

    PrepArgs pa;
    static const int widx[6] = {1,3,5,7,9,11};
    for (int i = 0; i < 6; ++i){
        pa.wp.w[i] = (const float*)d_in[widx[i]];
        pa.wp.o[i] = WT + (size_t)i*DD*DD;
    }
    pa.wp.zp = ZP;
    pa.wp.lf = Lf;
    pa.x = x; pa.g1 = g1; pa.be1 = be1; pa.ln = LN;
    unsigned short* WqT = pa.wp.o[0]; unsigned short* WkT = pa.wp.o[1];
    unsigned short* WvT = pa.wp.o[2]; unsigned short* WoT = pa.wp.o[3];
    unsigned short* W1T = pa.wp.o[4]; unsigned short* W2T = pa.wp.o[5];

    const dim3 blk(256);
    const float scale = 1.0f / sqrtf((float)SS);
    const dim3 gA(DD/128, MM/128);    // (8,64)

    // fused wtrans + LN1 (independent streams, one launch)
    prep<<<dim3(1536 + MM), blk, 0, stream>>>(pa);
    // fused Q + K + VT projections (1536 uniform tiles, one launch)
    proj_fused<<<dim3(1536), blk, 0, stream>>>(LN, WqT, WkT, WvT, bq, bk, bv, Qw, Kw, VTw);
    // attention: fused exp-scores (+row sums, triangular-packed) then PV (/rowsum)
    scores_mfma<<<dim3(544), blk, 0, stream>>>(Qw, Kw, Pw, Lf, scale);
    pv_mfma<<<dim3(DD/128, SS/128, BB), blk, 0, stream>>>(Pw, VTw, CTX, ZP, Lf);
    // h = ctx*WoT^T + bo + x (fp32)
    gemm_mfma<false,true,true,false><<<gA, blk, 0, stream>>>(CTX, WoT, bo, x, nullptr, Hf, DD, DD, DD, DD);
    ln_f32<<<dim3(MM), blk, 0, stream>>>(Hf, g2, be2, LN);
    // mid = relu(LN*W1T^T + b1)
    gemm_mfma<true,false,false,false><<<gA, blk, 0, stream>>>(LN, W1T, b1, nullptr, MIDw, nullptr, DD, DD, DD, DD);
    // out = mid*W2T^T + b2 + h
    gemm_mfma<false,true,true,false><<<gA, blk, 0, stream>>>(MIDw, W2T, b2, Hf, nullptr, outf, DD, DD, DD, DD);
}

// Round 9
// 334.328 us; speedup vs baseline: 1.1812x; 1.0361x over previous
//
#include <hip/hip_runtime.h>
#include <math.h>

#define BB 4
#define SS 2048
#define DD 1024
#define MM (BB*SS)                   // 8192
#define SD ((size_t)SS*DD)
#define MD ((size_t)MM*DD)           // 8,388,608
#define PPB ((size_t)2162688)        // packed P elems per batch

// ws (bf16 elems): Q@0 | K@MD | VT@2MD | P@3MD (4*PPB) | WT (6*DD*DD) | zpad(16) | L (8192 f32)
#define WT_OFF (3*MD + 4*PPB)
#define ZP_OFF (WT_OFF + 6*(size_t)DD*DD)
#define LF_OFF (ZP_OFF + 16)
#define REQ_WS ((LF_OFF + 16384) * 2)

constexpr float LN_EPS = 1e-6f;

typedef __attribute__((ext_vector_type(8))) __bf16 bf16x8;
typedef __attribute__((ext_vector_type(4))) float f32x4;

__device__ __forceinline__ unsigned short f2bfbits(float f){
    unsigned u = __float_as_uint(f);
    u += 0x7FFFu + ((u >> 16) & 1u);   // RNE
    return (unsigned short)(u >> 16);
}
__device__ __forceinline__ int rowWidth(int s){ return ((s >> 6) + 1) << 6; }
__device__ __forceinline__ size_t rowOff(int s){
    int g = s >> 6;
    return (size_t)4096 * (size_t)((g * (g + 1)) >> 1) + (size_t)(s & 63) * (size_t)((g + 1) << 6);
}
// async global->LDS, 16B per lane; LDS dest = wave-uniform base + lane*16
__device__ __forceinline__ void gl_lds(const unsigned short* g, unsigned short* l){
    __builtin_amdgcn_global_load_lds(
        (const __attribute__((address_space(1))) unsigned int*)g,
        (__attribute__((address_space(3))) unsigned int*)l, 16, 0, 0);
}

// XCD-aware bijective block swizzle (T1) — uniform-work launches only.
__device__ __forceinline__ int3 xcd_swz(){
    const int gx = gridDim.x, gy = gridDim.y, gz = gridDim.z;
    const int n = gx * gy * gz;
    int lin = blockIdx.x + gx * (blockIdx.y + gy * blockIdx.z);
    const int cpx = n >> 3;                 // n % 8 == 0 for all swizzled launches
    lin = (lin & 7) * cpx + (lin >> 3);     // bijection: XCD (lin&7) owns chunk
    int3 r;
    r.x = lin % gx; lin /= gx;
    r.y = lin % gy;
    r.z = lin / gy;
    return r;
}

__global__ __launch_bounds__(256)
void sentinel_kernel(float* __restrict__ out, const float val){
    out[(size_t)blockIdx.x * 256 + threadIdx.x] = val;
}

// ---------- prep: fused {weight transpose + zpad/L zero} and {LayerNorm1} ----------
struct WPack { const float* w[6]; unsigned short* o[6]; unsigned short* zp; float* lf; };
struct PrepArgs { WPack wp; const float* x; const float* g1; const float* be1;
                  unsigned short* ln; };
__global__ __launch_bounds__(256)
void prep(PrepArgs pa)
{
    const int id = blockIdx.x;
    const int tid = threadIdx.x;
    if (id < 1536){
        __shared__ float Ts[64][65];
        const int z = id >> 8, rem = id & 255;
        const int yy = rem >> 4, xx = rem & 15;
        const float* W = pa.wp.w[z];
        unsigned short* WT = pa.wp.o[z];
        const int r0 = yy*64, c0 = xx*64;
        if (id == 0 && tid < 16) pa.wp.zp[tid] = 0;
        if (id < 16){                       // zero L[8192] f32
            float2 z2 = {0.f, 0.f};
            ((float2*)pa.wp.lf)[id*256 + tid] = z2;
        }
        #pragma unroll
        for (int i = 0; i < 16; ++i){
            int lin = tid + i*256;
            int r = lin >> 6, c = lin & 63;
            Ts[r][c] = W[(size_t)(r0+r)*DD + c0+c];
        }
        __syncthreads();
        #pragma unroll
        for (int i = 0; i < 16; ++i){
            int lin = tid + i*256;
            int r = lin >> 6, c = lin & 63;
            WT[(size_t)(c0+r)*DD + r0+c] = f2bfbits(Ts[c][r]);
        }
    } else {
        __shared__ float red[4];
        const int row = id - 1536;
        float4 xv = ((const float4*)(pa.x + (size_t)row*DD))[tid];
        float v[4] = {xv.x, xv.y, xv.z, xv.w};
        float s = v[0]+v[1]+v[2]+v[3];
        #pragma unroll
        for (int off = 32; off > 0; off >>= 1) s += __shfl_down(s, off, 64);
        if ((tid & 63) == 0) red[tid >> 6] = s;
        __syncthreads();
        const float mean = (red[0]+red[1]+red[2]+red[3]) * (1.0f/DD);
        __syncthreads();
        float q = 0.f;
        #pragma unroll
        for (int i = 0; i < 4; ++i){ float d = v[i]-mean; q += d*d; }
        #pragma unroll
        for (int off = 32; off > 0; off >>= 1) q += __shfl_down(q, off, 64);
        if ((tid & 63) == 0) red[tid >> 6] = q;
        __syncthreads();
        const float var = (red[0]+red[1]+red[2]+red[3]) * (1.0f/(DD-1));
        const float inv = 1.0f/(sqrtf(var) + LN_EPS);
        float4 g4 = ((const float4*)pa.g1)[tid];
        float4 b4 = ((const float4*)pa.be1)[tid];
        ushort4 o;
        o.x = f2bfbits(g4.x*(v[0]-mean)*inv + b4.x);
        o.y = f2bfbits(g4.y*(v[1]-mean)*inv + b4.y);
        o.z = f2bfbits(g4.z*(v[2]-mean)*inv + b4.z);
        o.w = f2bfbits(g4.w*(v[3]-mean)*inv + b4.w);
        ((ushort4*)(pa.ln + (size_t)row*DD))[tid] = o;
    }
}

// ---------- LayerNorm: fp32 in -> bf16 out (standalone, for LN2) ----------
__global__ __launch_bounds__(256)
void ln_f32(const float* __restrict__ x, const float* __restrict__ gamma,
            const float* __restrict__ beta, unsigned short* __restrict__ out)
{
    __shared__ float red[4];
    const int row = blockIdx.x;
    const int tid = threadIdx.x;
    float4 xv = ((const float4*)(x + (size_t)row*DD))[tid];
    float v[4] = {xv.x, xv.y, xv.z, xv.w};
    float s = v[0]+v[1]+v[2]+v[3];
    #pragma unroll
    for (int off = 32; off > 0; off >>= 1) s += __shfl_down(s, off, 64);
    if ((tid & 63) == 0) red[tid >> 6] = s;
    __syncthreads();
    const float mean = (red[0]+red[1]+red[2]+red[3]) * (1.0f/DD);
    __syncthreads();
    float q = 0.f;
    #pragma unroll
    for (int i = 0; i < 4; ++i){ float d = v[i]-mean; q += d*d; }
    #pragma unroll
    for (int off = 32; off > 0; off >>= 1) q += __shfl_down(q, off, 64);
    if ((tid & 63) == 0) red[tid >> 6] = q;
    __syncthreads();
    const float var = (red[0]+red[1]+red[2]+red[3]) * (1.0f/(DD-1));
    const float inv = 1.0f/(sqrtf(var) + LN_EPS);
    float4 g4 = ((const float4*)gamma)[tid];
    float4 b4 = ((const float4*)beta)[tid];
    ushort4 o;
    o.x = f2bfbits(g4.x*(v[0]-mean)*inv + b4.x);
    o.y = f2bfbits(g4.y*(v[1]-mean)*inv + b4.y);
    o.z = f2bfbits(g4.z*(v[2]-mean)*inv + b4.z);
    o.w = f2bfbits(g4.w*(v[3]-mean)*inv + b4.w);
    ((ushort4*)(out + (size_t)row*DD))[tid] = o;
}

// =========== double-buffered MFMA main loop (iso-occupancy pipelining) ===========
// 128x128 tile, BK=64, 4 waves 2x2. TWO static buffer pairs (64 KB -> still
// 2 blocks/CU). Counted vmcnt(8): each tile's loads get a full compute phase
// to land. Helps kernels whose staging hits L2 (scores/pv/dense, R8: -22us);
// HURTS HBM-miss-heavy staging (proj, R8: +5us) -> proj uses the sync core.
template<bool PACKED>
__device__ __forceinline__ void mfma_db(
    const unsigned short* const ga[4], const unsigned short* const gb[4],
    const int* pw, const unsigned short* zpad, const int NT,
    f32x4 acc[4][4], const int wave, const int lane,
    unsigned short (&As0)[8192], unsigned short (&Bs0)[8192],
    unsigned short (&As1)[8192], unsigned short (&Bs1)[8192])
{
    const int quad = lane >> 4, l15 = lane & 15;
    const int wm = ((wave >> 1) & 1) * 64, wn = (wave & 1) * 64;

    auto stage = [&](unsigned short (&Ab)[8192], unsigned short (&Bb)[8192], const int koff){
        #pragma unroll
        for (int c = 0; c < 4; ++c){
            const unsigned short* gp = ga[c] + koff;
            if constexpr (PACKED) { if (koff >= pw[c]) gp = zpad; }
            gl_lds(gp, &Ab[(wave*4+c)*512]);
            gl_lds(gb[c] + koff, &Bb[(wave*4+c)*512]);
        }
    };
    auto compute = [&](unsigned short (&Ab)[8192], unsigned short (&Bb)[8192]){
        #pragma unroll
        for (int kk = 0; kk < 2; ++kk){
            bf16x8 af[4], bfr[4];
            #pragma unroll
            for (int t = 0; t < 4; ++t){
                const int ra = wm + t*16 + l15, rb = wn + t*16 + l15, gi = kk*4 + quad;
                af[t]  = *(const bf16x8*)&Ab[ra*64 + (((gi + ra) & 7) << 3)];
                bfr[t] = *(const bf16x8*)&Bb[rb*64 + (((gi + rb) & 7) << 3)];
            }
            #pragma unroll
            for (int i = 0; i < 4; ++i)
                #pragma unroll
                for (int j = 0; j < 4; ++j)
                    acc[i][j] = __builtin_amdgcn_mfma_f32_16x16x32_bf16(af[i], bfr[j], acc[i][j], 0, 0, 0);
        }
    };

    stage(As0, Bs0, 0);
    const int half = NT >> 1;
    for (int i = 0; i < half; ++i){
        stage(As1, Bs1, (2*i + 1) << 6);
        asm volatile("s_waitcnt vmcnt(8)" ::: "memory");   // buf0 landed; buf1 in flight
        __builtin_amdgcn_s_barrier();
        __builtin_amdgcn_sched_barrier(0);
        compute(As0, Bs0);
        __builtin_amdgcn_s_barrier();                      // buf0 readers drained
        if (i + 1 < half){
            stage(As0, Bs0, (2*i + 2) << 6);
            asm volatile("s_waitcnt vmcnt(8)" ::: "memory");   // buf1 landed
        } else {
            asm volatile("s_waitcnt vmcnt(0)" ::: "memory");   // tail drain
        }
        __builtin_amdgcn_s_barrier();
        __builtin_amdgcn_sched_barrier(0);
        compute(As1, Bs1);
        __builtin_amdgcn_s_barrier();                      // buf1 readers drained
    }
}

__device__ __forceinline__ void mk_chunks(const unsigned short* base, size_t ld, int r0,
                                          int wave, int lane, const unsigned short* g[4]){
    #pragma unroll
    for (int c = 0; c < 4; ++c){
        const int mr = (wave*4 + c)*8 + (lane >> 3);
        const int gk = ((lane & 7) - mr) & 7;
        g[c] = base + (size_t)(r0 + mr)*ld + gk*8;
    }
}

#define DECL_DB \
    __shared__ unsigned short As0[8192]; \
    __shared__ unsigned short Bs0[8192]; \
    __shared__ unsigned short As1[8192]; \
    __shared__ unsigned short Bs1[8192];

// =========== GEMM core wrapper (double-buffered) ===========
template<bool RELU, bool RES, bool OUTF, bool BIAS_M>
__device__ __forceinline__ void gemm_core(
    const unsigned short* __restrict__ A, const unsigned short* __restrict__ B,
    const float* __restrict__ bias, const float* __restrict__ resF,
    unsigned short* __restrict__ outB, float* __restrict__ outF,
    const int N, const int K, const int lda, const int ldb,
    const int m0, const int n0,
    unsigned short (&As0)[8192], unsigned short (&Bs0)[8192],
    unsigned short (&As1)[8192], unsigned short (&Bs1)[8192])
{
    const int tid = threadIdx.x, lane = tid & 63, wave = tid >> 6;
    const int wm = ((wave >> 1) & 1) * 64, wn = (wave & 1) * 64;
    const int quad = lane >> 4, l15 = lane & 15;
    const unsigned short* ga[4]; const unsigned short* gb[4];
    mk_chunks(A, lda, m0, wave, lane, ga);
    mk_chunks(B, ldb, n0, wave, lane, gb);
    f32x4 acc[4][4] = {};
    mfma_db<false>(ga, gb, nullptr, nullptr, K >> 6, acc, wave, lane, As0, Bs0, As1, Bs1);
    #pragma unroll
    for (int i = 0; i < 4; ++i){
        #pragma unroll
        for (int r = 0; r < 4; ++r){
            const int m = m0 + wm + i*16 + quad*4 + r;
            const float bm = BIAS_M ? bias[m] : 0.f;
            #pragma unroll
            for (int j = 0; j < 4; ++j){
                const int n = n0 + wn + j*16 + l15;
                float v = acc[i][j][r] + (BIAS_M ? bm : bias[n]);
                if constexpr (RELU) v = fmaxf(v, 0.f);
                if constexpr (RES) v += resF[(size_t)m*N + n];
                if constexpr (OUTF) outF[(size_t)m*N + n] = v;
                else outB[(size_t)m*N + n] = f2bfbits(v);
            }
        }
    }
}

// =========== GEMM core, single-buffer sync loop (for HBM-miss-heavy proj) ===========
template<bool RELU, bool RES, bool OUTF, bool BIAS_M>
__device__ __forceinline__ void gemm_core_sb(
    const unsigned short* __restrict__ A, const unsigned short* __restrict__ B,
    const float* __restrict__ bias, const float* __restrict__ resF,
    unsigned short* __restrict__ outB, float* __restrict__ outF,
    const int N, const int K, const int lda, const int ldb,
    const int m0, const int n0,
    unsigned short* As, unsigned short* Bs)
{
    const int tid = threadIdx.x, lane = tid & 63, wave = tid >> 6;
    const int wm = ((wave >> 1) & 1) * 64, wn = (wave & 1) * 64;
    const int quad = lane >> 4, l15 = lane & 15;
    const unsigned short* ga[4]; const unsigned short* gb[4];
    mk_chunks(A, lda, m0, wave, lane, ga);
    mk_chunks(B, ldb, n0, wave, lane, gb);
    f32x4 acc[4][4] = {};
    for (int k0 = 0; k0 < K; k0 += 64){
        #pragma unroll
        for (int c = 0; c < 4; ++c){
            gl_lds(ga[c] + k0, &As[(wave*4+c)*512]);
            gl_lds(gb[c] + k0, &Bs[(wave*4+c)*512]);
        }
        __syncthreads();
        #pragma unroll
        for (int kk = 0; kk < 2; ++kk){
            bf16x8 af[4], bfr[4];
            #pragma unroll
            for (int t = 0; t < 4; ++t){
                const int ra = wm + t*16 + l15, rb = wn + t*16 + l15, gi = kk*4 + quad;
                af[t]  = *(const bf16x8*)&As[ra*64 + (((gi + ra) & 7) << 3)];
                bfr[t] = *(const bf16x8*)&Bs[rb*64 + (((gi + rb) & 7) << 3)];
            }
            #pragma unroll
            for (int i = 0; i < 4; ++i)
                #pragma unroll
                for (int j = 0; j < 4; ++j)
                    acc[i][j] = __builtin_amdgcn_mfma_f32_16x16x32_bf16(af[i], bfr[j], acc[i][j], 0, 0, 0);
        }
        __syncthreads();
    }
    #pragma unroll
    for (int i = 0; i < 4; ++i){
        #pragma unroll
        for (int r = 0; r < 4; ++r){
            const int m = m0 + wm + i*16 + quad*4 + r;
            const float bm = BIAS_M ? bias[m] : 0.f;
            #pragma unroll
            for (int j = 0; j < 4; ++j){
                const int n = n0 + wn + j*16 + l15;
                float v = acc[i][j][r] + (BIAS_M ? bm : bias[n]);
                if constexpr (RELU) v = fmaxf(v, 0.f);
                if constexpr (RES) v += resF[(size_t)m*N + n];
                if constexpr (OUTF) outF[(size_t)m*N + n] = v;
                else outB[(size_t)m*N + n] = f2bfbits(v);
            }
        }
    }
}

// generic single GEMM (double-buffered)
template<bool RELU, bool RES, bool OUTF, bool BIAS_M>
__global__ __launch_bounds__(256)
void gemm_mfma(const unsigned short* __restrict__ A, const unsigned short* __restrict__ B,
               const float* __restrict__ bias, const float* __restrict__ resF,
               unsigned short* __restrict__ outB, float* __restrict__ outF,
               const int N, const int K, const int lda, const int ldb)
{
    DECL_DB
    const int3 b = xcd_swz();
    gemm_core<RELU,RES,OUTF,BIAS_M>(A, B, bias, resF, outB, outF, N, K, lda, ldb,
                                    b.y*128, b.x*128, As0, Bs0, As1, Bs1);
}

// ---------- fused Q/K/VT projections: 1536 uniform tiles in ONE launch ----------
// Single-buffer core (R8: db hurt this HBM-miss-heavy kernel). VT ids REORDERED
// (m0 fastest) so 8 consecutive ids share one LN B-panel and WvT stays L2-hot;
// previous n0-fastest order streamed all 16.8MB of LN once per WvT m-group
// (~134MB logical re-read -> the measured 99MB FETCH).
__global__ __launch_bounds__(256)
void proj_fused(const unsigned short* __restrict__ LN,
                const unsigned short* __restrict__ WqT, const unsigned short* __restrict__ WkT,
                const unsigned short* __restrict__ WvT,
                const float* __restrict__ bq, const float* __restrict__ bk,
                const float* __restrict__ bv,
                unsigned short* __restrict__ Qw, unsigned short* __restrict__ Kw,
                unsigned short* __restrict__ VTw)
{
    __shared__ unsigned short As[8192];
    __shared__ unsigned short Bs[8192];
    const int lin = blockIdx.x;                    // 1536
    const int id = (lin & 7) * 192 + (lin >> 3);   // chunked XCD swizzle
    if (id < 1024){
        const bool isK = (id >= 512);
        const int q = id & 511;
        const int n0 = (q & 7) * 128, m0 = (q >> 3) * 128;   // n over DD, m over MM
        gemm_core_sb<false,false,false,false>(LN, isK ? WkT : WqT, isK ? bk : bq, nullptr,
                                              isK ? Kw : Qw, nullptr, DD, DD, DD, DD,
                                              m0, n0, As, Bs);
    } else {
        const int q = id - 1024;
        const int m0 = (q & 7) * 128, n0 = (q >> 3) * 128;   // m over DD, n over MM (reordered)
        gemm_core_sb<false,false,false,true>(WvT, LN, bv, nullptr, VTw, nullptr,
                                             MM, DD, DD, DD, m0, n0, As, Bs);
    }
}

// ---------- scores: packed P = exp(Q*K^T * scale), causal, UNNORMALIZED ----------
__global__ __launch_bounds__(256)
void scores_mfma(const unsigned short* __restrict__ Qb, const unsigned short* __restrict__ Kb,
                 unsigned short* __restrict__ Pb, float* __restrict__ Lf, const float scale)
{
    const int lin = blockIdx.x;                    // 544 = 4 * 136
    const int id = (lin & 7) * 68 + (lin >> 3);    // chunked XCD swizzle
    const int z = id / 136;
    const int idx = id - z * 136;
    int y = (int)((sqrtf(8.f * (float)idx + 1.f) - 1.f) * 0.5f);
    while ((y + 1) * (y + 2) / 2 <= idx) ++y;      // guard float error
    while (y * (y + 1) / 2 > idx) --y;
    const int x = idx - y * (y + 1) / 2;           // x <= y
    const int s0 = y * 128, t0 = x * 128;

    const unsigned short* Q  = Qb + (size_t)z*SD;
    const unsigned short* Km = Kb + (size_t)z*SD;
    unsigned short* P        = Pb + (size_t)z*PPB;
    float* L                 = Lf + (size_t)z*SS;
    DECL_DB
    const int tid = threadIdx.x, lane = tid & 63, wave = tid >> 6;
    const int wm = ((wave >> 1) & 1) * 64, wn = (wave & 1) * 64;
    const int quad = lane >> 4, l15 = lane & 15;
    const unsigned short* ga[4]; const unsigned short* gb[4];
    mk_chunks(Q,  DD, s0, wave, lane, ga);
    mk_chunks(Km, DD, t0, wave, lane, gb);
    f32x4 acc[4][4] = {};
    mfma_db<false>(ga, gb, nullptr, nullptr, DD >> 6, acc, wave, lane, As0, Bs0, As1, Bs1);

    #pragma unroll
    for (int i = 0; i < 4; ++i){
        #pragma unroll
        for (int r = 0; r < 4; ++r){
            const int s = s0 + wm + i*16 + quad*4 + r;
            const int width = rowWidth(s);
            unsigned short* pr = P + rowOff(s);
            float psum = 0.f;
            if (t0 + wn < width){                    // 64-chunk uniform in/out
                #pragma unroll
                for (int j = 0; j < 4; ++j){
                    const int t = t0 + wn + j*16 + l15;
                    const float e = (t <= s) ? __expf(acc[i][j][r] * scale) : 0.f;
                    pr[t] = f2bfbits(e);
                    psum += e;
                }
                #pragma unroll
                for (int off = 8; off > 0; off >>= 1) psum += __shfl_xor(psum, off, 64);
                if (l15 == 0) atomicAdd(&L[s], psum);
            }
        }
    }
}

// ---------- ctx = (P @ V) / l ; A=packed unnormalized P, B=VT[d][tok] ----------
// Causal-balance remap: y' = (z>=2) ? 15-y : y (complementary co-resident pairs).
__global__ __launch_bounds__(256)
void pv_mfma(const unsigned short* __restrict__ Pb, const unsigned short* __restrict__ VT,
             unsigned short* __restrict__ Cb, const unsigned short* __restrict__ zpad,
             const float* __restrict__ Lf)
{
    const int yr = blockIdx.y;
    const int y  = (blockIdx.z >= 2) ? (15 - yr) : yr;
    const int s0 = y*128, n0 = blockIdx.x*128;
    const unsigned short* P = Pb + (size_t)blockIdx.z*PPB;
    unsigned short* C       = Cb + (size_t)blockIdx.z*SD;
    const float* L          = Lf + (size_t)blockIdx.z*SS;
    const int bcol = blockIdx.z*SS;
    DECL_DB
    const int tid = threadIdx.x, lane = tid & 63, wave = tid >> 6;
    const int wm = ((wave >> 1) & 1) * 64, wn = (wave & 1) * 64;
    const int quad = lane >> 4, l15 = lane & 15;
    const unsigned short* ga[4]; const unsigned short* gb[4]; int pw[4];
    #pragma unroll
    for (int c = 0; c < 4; ++c){
        const int mr = (wave*4 + c)*8 + (lane >> 3);
        const int gk = ((lane & 7) - mr) & 7;
        const int s = s0 + mr;
        pw[c] = rowWidth(s) - gk*8;                 // chunk valid iff koff < pw
        ga[c] = P + rowOff(s) + gk*8;
    }
    mk_chunks(VT + bcol, MM, n0, wave, lane, gb);
    f32x4 acc[4][4] = {};
    const int NT = (s0 >> 6) + 2;                   // 2y+2, even
    mfma_db<true>(ga, gb, pw, zpad, NT, acc, wave, lane, As0, Bs0, As1, Bs1);

    #pragma unroll
    for (int i = 0; i < 4; ++i){
        #pragma unroll
        for (int r = 0; r < 4; ++r){
            const int s = s0 + wm + i*16 + quad*4 + r;
            const float linv = 1.0f / L[s];
            #pragma unroll
            for (int j = 0; j < 4; ++j){
                const int n = n0 + wn + j*16 + l15;
                C[(size_t)s*DD + n] = f2bfbits(acc[i][j][r] * linv);
            }
        }
    }
}

extern "C" void kernel_launch(void* const* d_in, const int* in_sizes, int n_in,
                              void* d_out, int out_size, void* d_ws, size_t ws_size,
                              hipStream_t stream)
{
    (void)in_sizes; (void)n_in; (void)out_size;
    const float* x   = (const float*)d_in[0];
    const float* bq  = (const float*)d_in[2];
    const float* bk  = (const float*)d_in[4];
    const float* bv  = (const float*)d_in[6];
    const float* bo  = (const float*)d_in[8];
    const float* b1  = (const float*)d_in[10];
    const float* b2  = (const float*)d_in[12];
    const float* g1  = (const float*)d_in[13];
    const float* be1 = (const float*)d_in[14];
    const float* g2  = (const float*)d_in[15];
    const float* be2 = (const float*)d_in[16];
    float* outf = (float*)d_out;

    if (ws_size < (size_t)REQ_WS){
        sentinel_kernel<<<dim3((unsigned)(MD/256)), dim3(256), 0, stream>>>(outf, 1.0e9f);
        return;
    }

    unsigned short* wsb = (unsigned short*)d_ws;
    unsigned short* Qw  = wsb;                 // -> ctx
    unsigned short* Kw  = wsb + MD;            // \ -> Hf (fp32 spans K+VT)
    unsigned short* VTw = wsb + 2*MD;          // /
    unsigned short* Pw  = wsb + 3*MD;          // packed P -> mid
    unsigned short* WT  = wsb + WT_OFF;
    unsigned short* ZP  = wsb + ZP_OFF;
    float*          Lf  = (float*)(wsb + LF_OFF);
    float*          Hf  = (float*)Kw;
    unsigned short* CTX = Qw;
    unsigned short* MIDw= Pw;
    unsigned short* LN  = (unsigned short*)d_out;   // LN1/LN2 scratch in d_out

    PrepArgs pa;
    static const int widx[6] = {1,3,5,7,9,11};
    for (int i = 0; i < 6; ++i){
        pa.wp.w[i] = (const float*)d_in[widx[i]];
        pa.wp.o[i] = WT + (size_t)i*DD*DD;
    }
    pa.wp.zp = ZP;
    pa.wp.lf = Lf;
    pa.x = x; pa.g1 = g1; pa.be1 = be1; pa.ln = LN;
    unsigned short* WqT = pa.wp.o[0]; unsigned short* WkT = pa.wp.o[1];
    unsigned short* WvT = pa.wp.o[2]; unsigned short* WoT = pa.wp.o[3];
    unsigned short* W1T = pa.wp.o[4]; unsigned short* W2T = pa.wp.o[5];

    const dim3 blk(256);
    const float scale = 1.0f / sqrtf((float)SS);
    const dim3 gA(DD/128, MM/128);    // (8,64)

    // fused wtrans + LN1 (independent streams, one launch)
    prep<<<dim3(1536 + MM), blk, 0, stream>>>(pa);
    // fused Q + K + VT projections (1536 uniform tiles, one launch)
    proj_fused<<<dim3(1536), blk, 0, stream>>>(LN, WqT, WkT, WvT, bq, bk, bv, Qw, Kw, VTw);
    // attention: fused exp-scores (+row sums, triangular-packed) then PV (/rowsum)
    scores_mfma<<<dim3(544), blk, 0, stream>>>(Qw, Kw, Pw, Lf, scale);
    pv_mfma<<<dim3(DD/128, SS/128, BB), blk, 0, stream>>>(Pw, VTw, CTX, ZP, Lf);
    // h = ctx*WoT^T + bo + x (fp32)
    gemm_mfma<false,true,true,false><<<gA, blk, 0, stream>>>(CTX, WoT, bo, x, nullptr, Hf, DD, DD, DD, DD);
    ln_f32<<<dim3(MM), blk, 0, stream>>>(Hf, g2, be2, LN);
    // mid = relu(LN*W1T^T + b1)
    gemm_mfma<true,false,false,false><<<gA, blk, 0, stream>>>(LN, W1T, b1, nullptr, MIDw, nullptr, DD, DD, DD, DD);
    // out = mid*W2T^T + b2 + h
    gemm_mfma<false,true,true,false><<<gA, blk, 0, stream>>>(MIDw, W2T, b2, Hf, nullptr, outf, DD, DD, DD, DD);
}

// Round 10
// 333.357 us; speedup vs baseline: 1.1846x; 1.0029x over previous
//
#include <hip/hip_runtime.h>
#include <math.h>

#define BB 4
#define SS 2048
#define DD 1024
#define MM (BB*SS)                   // 8192
#define SD ((size_t)SS*DD)
#define MD ((size_t)MM*DD)           // 8,388,608
#define PPB ((size_t)2162688)        // packed P elems per batch

// ws (bf16 elems): Q@0 | K@MD | VT@2MD | P@3MD (4*PPB) | WT (6*DD*DD) | zpad(16) | L (8192 f32)
#define WT_OFF (3*MD + 4*PPB)
#define ZP_OFF (WT_OFF + 6*(size_t)DD*DD)
#define LF_OFF (ZP_OFF + 16)
#define REQ_WS ((LF_OFF + 16384) * 2)

constexpr float LN_EPS = 1e-6f;

typedef __attribute__((ext_vector_type(8))) __bf16 bf16x8;
typedef __attribute__((ext_vector_type(4))) float f32x4;

__device__ __forceinline__ unsigned short f2bfbits(float f){
    unsigned u = __float_as_uint(f);
    u += 0x7FFFu + ((u >> 16) & 1u);   // RNE
    return (unsigned short)(u >> 16);
}
__device__ __forceinline__ int rowWidth(int s){ return ((s >> 6) + 1) << 6; }
__device__ __forceinline__ size_t rowOff(int s){
    int g = s >> 6;
    return (size_t)4096 * (size_t)((g * (g + 1)) >> 1) + (size_t)(s & 63) * (size_t)((g + 1) << 6);
}
// async global->LDS, 16B per lane; LDS dest = wave-uniform base + lane*16
__device__ __forceinline__ void gl_lds(const unsigned short* g, unsigned short* l){
    __builtin_amdgcn_global_load_lds(
        (const __attribute__((address_space(1))) unsigned int*)g,
        (__attribute__((address_space(3))) unsigned int*)l, 16, 0, 0);
}

// XCD-aware bijective block swizzle (T1) — uniform-work launches only.
__device__ __forceinline__ int3 xcd_swz(){
    const int gx = gridDim.x, gy = gridDim.y, gz = gridDim.z;
    const int n = gx * gy * gz;
    int lin = blockIdx.x + gx * (blockIdx.y + gy * blockIdx.z);
    const int cpx = n >> 3;                 // n % 8 == 0 for all swizzled launches
    lin = (lin & 7) * cpx + (lin >> 3);     // bijection: XCD (lin&7) owns chunk
    int3 r;
    r.x = lin % gx; lin /= gx;
    r.y = lin % gy;
    r.z = lin / gy;
    return r;
}

__global__ __launch_bounds__(256)
void sentinel_kernel(float* __restrict__ out, const float val){
    out[(size_t)blockIdx.x * 256 + threadIdx.x] = val;
}

// ---------- prep: fused {weight transpose + zpad/L zero} and {LayerNorm1} ----------
struct WPack { const float* w[6]; unsigned short* o[6]; unsigned short* zp; float* lf; };
struct PrepArgs { WPack wp; const float* x; const float* g1; const float* be1;
                  unsigned short* ln; };
__global__ __launch_bounds__(256)
void prep(PrepArgs pa)
{
    const int id = blockIdx.x;
    const int tid = threadIdx.x;
    if (id < 1536){
        __shared__ float Ts[64][65];
        const int z = id >> 8, rem = id & 255;
        const int yy = rem >> 4, xx = rem & 15;
        const float* W = pa.wp.w[z];
        unsigned short* WT = pa.wp.o[z];
        const int r0 = yy*64, c0 = xx*64;
        if (id == 0 && tid < 16) pa.wp.zp[tid] = 0;
        if (id < 16){                       // zero L[8192] f32
            float2 z2 = {0.f, 0.f};
            ((float2*)pa.wp.lf)[id*256 + tid] = z2;
        }
        #pragma unroll
        for (int i = 0; i < 16; ++i){
            int lin = tid + i*256;
            int r = lin >> 6, c = lin & 63;
            Ts[r][c] = W[(size_t)(r0+r)*DD + c0+c];
        }
        __syncthreads();
        #pragma unroll
        for (int i = 0; i < 16; ++i){
            int lin = tid + i*256;
            int r = lin >> 6, c = lin & 63;
            WT[(size_t)(c0+r)*DD + r0+c] = f2bfbits(Ts[c][r]);
        }
    } else {
        __shared__ float red[4];
        const int row = id - 1536;
        float4 xv = ((const float4*)(pa.x + (size_t)row*DD))[tid];
        float v[4] = {xv.x, xv.y, xv.z, xv.w};
        float s = v[0]+v[1]+v[2]+v[3];
        #pragma unroll
        for (int off = 32; off > 0; off >>= 1) s += __shfl_down(s, off, 64);
        if ((tid & 63) == 0) red[tid >> 6] = s;
        __syncthreads();
        const float mean = (red[0]+red[1]+red[2]+red[3]) * (1.0f/DD);
        __syncthreads();
        float q = 0.f;
        #pragma unroll
        for (int i = 0; i < 4; ++i){ float d = v[i]-mean; q += d*d; }
        #pragma unroll
        for (int off = 32; off > 0; off >>= 1) q += __shfl_down(q, off, 64);
        if ((tid & 63) == 0) red[tid >> 6] = q;
        __syncthreads();
        const float var = (red[0]+red[1]+red[2]+red[3]) * (1.0f/(DD-1));
        const float inv = 1.0f/(sqrtf(var) + LN_EPS);
        float4 g4 = ((const float4*)pa.g1)[tid];
        float4 b4 = ((const float4*)pa.be1)[tid];
        ushort4 o;
        o.x = f2bfbits(g4.x*(v[0]-mean)*inv + b4.x);
        o.y = f2bfbits(g4.y*(v[1]-mean)*inv + b4.y);
        o.z = f2bfbits(g4.z*(v[2]-mean)*inv + b4.z);
        o.w = f2bfbits(g4.w*(v[3]-mean)*inv + b4.w);
        ((ushort4*)(pa.ln + (size_t)row*DD))[tid] = o;
    }
}

// ---------- LayerNorm: fp32 in -> bf16 out (standalone, for LN2) ----------
__global__ __launch_bounds__(256)
void ln_f32(const float* __restrict__ x, const float* __restrict__ gamma,
            const float* __restrict__ beta, unsigned short* __restrict__ out)
{
    __shared__ float red[4];
    const int row = blockIdx.x;
    const int tid = threadIdx.x;
    float4 xv = ((const float4*)(x + (size_t)row*DD))[tid];
    float v[4] = {xv.x, xv.y, xv.z, xv.w};
    float s = v[0]+v[1]+v[2]+v[3];
    #pragma unroll
    for (int off = 32; off > 0; off >>= 1) s += __shfl_down(s, off, 64);
    if ((tid & 63) == 0) red[tid >> 6] = s;
    __syncthreads();
    const float mean = (red[0]+red[1]+red[2]+red[3]) * (1.0f/DD);
    __syncthreads();
    float q = 0.f;
    #pragma unroll
    for (int i = 0; i < 4; ++i){ float d = v[i]-mean; q += d*d; }
    #pragma unroll
    for (int off = 32; off > 0; off >>= 1) q += __shfl_down(q, off, 64);
    if ((tid & 63) == 0) red[tid >> 6] = q;
    __syncthreads();
    const float var = (red[0]+red[1]+red[2]+red[3]) * (1.0f/(DD-1));
    const float inv = 1.0f/(sqrtf(var) + LN_EPS);
    float4 g4 = ((const float4*)gamma)[tid];
    float4 b4 = ((const float4*)beta)[tid];
    ushort4 o;
    o.x = f2bfbits(g4.x*(v[0]-mean)*inv + b4.x);
    o.y = f2bfbits(g4.y*(v[1]-mean)*inv + b4.y);
    o.z = f2bfbits(g4.z*(v[2]-mean)*inv + b4.z);
    o.w = f2bfbits(g4.w*(v[3]-mean)*inv + b4.w);
    ((ushort4*)(out + (size_t)row*DD))[tid] = o;
}

// =========== double-buffered MFMA main loop (iso-occupancy pipelining) ===========
// 128x128 tile, BK=64, 4 waves 2x2. TWO static buffer pairs (64 KB -> still
// 2 blocks/CU). Counted vmcnt(8): each tile's loads get a full compute phase
// to land. Proven +15-20% on L2-resident staging (scores/pv/dense, R8).
template<bool PACKED>
__device__ __forceinline__ void mfma_db(
    const unsigned short* const ga[4], const unsigned short* const gb[4],
    const int* pw, const unsigned short* zpad, const int NT,
    f32x4 acc[4][4], const int wave, const int lane,
    unsigned short (&As0)[8192], unsigned short (&Bs0)[8192],
    unsigned short (&As1)[8192], unsigned short (&Bs1)[8192])
{
    const int quad = lane >> 4, l15 = lane & 15;
    const int wm = ((wave >> 1) & 1) * 64, wn = (wave & 1) * 64;

    auto stage = [&](unsigned short (&Ab)[8192], unsigned short (&Bb)[8192], const int koff){
        #pragma unroll
        for (int c = 0; c < 4; ++c){
            const unsigned short* gp = ga[c] + koff;
            if constexpr (PACKED) { if (koff >= pw[c]) gp = zpad; }
            gl_lds(gp, &Ab[(wave*4+c)*512]);
            gl_lds(gb[c] + koff, &Bb[(wave*4+c)*512]);
        }
    };
    auto compute = [&](unsigned short (&Ab)[8192], unsigned short (&Bb)[8192]){
        #pragma unroll
        for (int kk = 0; kk < 2; ++kk){
            bf16x8 af[4], bfr[4];
            #pragma unroll
            for (int t = 0; t < 4; ++t){
                const int ra = wm + t*16 + l15, rb = wn + t*16 + l15, gi = kk*4 + quad;
                af[t]  = *(const bf16x8*)&Ab[ra*64 + (((gi + ra) & 7) << 3)];
                bfr[t] = *(const bf16x8*)&Bb[rb*64 + (((gi + rb) & 7) << 3)];
            }
            #pragma unroll
            for (int i = 0; i < 4; ++i)
                #pragma unroll
                for (int j = 0; j < 4; ++j)
                    acc[i][j] = __builtin_amdgcn_mfma_f32_16x16x32_bf16(af[i], bfr[j], acc[i][j], 0, 0, 0);
        }
    };

    stage(As0, Bs0, 0);
    const int half = NT >> 1;
    for (int i = 0; i < half; ++i){
        stage(As1, Bs1, (2*i + 1) << 6);
        asm volatile("s_waitcnt vmcnt(8)" ::: "memory");   // buf0 landed; buf1 in flight
        __builtin_amdgcn_s_barrier();
        __builtin_amdgcn_sched_barrier(0);
        compute(As0, Bs0);
        __builtin_amdgcn_s_barrier();                      // buf0 readers drained
        if (i + 1 < half){
            stage(As0, Bs0, (2*i + 2) << 6);
            asm volatile("s_waitcnt vmcnt(8)" ::: "memory");   // buf1 landed
        } else {
            asm volatile("s_waitcnt vmcnt(0)" ::: "memory");   // tail drain
        }
        __builtin_amdgcn_s_barrier();
        __builtin_amdgcn_sched_barrier(0);
        compute(As1, Bs1);
        __builtin_amdgcn_s_barrier();                      // buf1 readers drained
    }
}

__device__ __forceinline__ void mk_chunks(const unsigned short* base, size_t ld, int r0,
                                          int wave, int lane, const unsigned short* g[4]){
    #pragma unroll
    for (int c = 0; c < 4; ++c){
        const int mr = (wave*4 + c)*8 + (lane >> 3);
        const int gk = ((lane & 7) - mr) & 7;
        g[c] = base + (size_t)(r0 + mr)*ld + gk*8;
    }
}

#define DECL_DB \
    __shared__ unsigned short As0[8192]; \
    __shared__ unsigned short Bs0[8192]; \
    __shared__ unsigned short As1[8192]; \
    __shared__ unsigned short Bs1[8192];

// =========== GEMM core wrapper (double-buffered) ===========
template<bool RELU, bool RES, bool OUTF, bool BIAS_M>
__device__ __forceinline__ void gemm_core(
    const unsigned short* __restrict__ A, const unsigned short* __restrict__ B,
    const float* __restrict__ bias, const float* __restrict__ resF,
    unsigned short* __restrict__ outB, float* __restrict__ outF,
    const int N, const int K, const int lda, const int ldb,
    const int m0, const int n0,
    unsigned short (&As0)[8192], unsigned short (&Bs0)[8192],
    unsigned short (&As1)[8192], unsigned short (&Bs1)[8192])
{
    const int tid = threadIdx.x, lane = tid & 63, wave = tid >> 6;
    const int wm = ((wave >> 1) & 1) * 64, wn = (wave & 1) * 64;
    const int quad = lane >> 4, l15 = lane & 15;
    const unsigned short* ga[4]; const unsigned short* gb[4];
    mk_chunks(A, lda, m0, wave, lane, ga);
    mk_chunks(B, ldb, n0, wave, lane, gb);
    f32x4 acc[4][4] = {};
    mfma_db<false>(ga, gb, nullptr, nullptr, K >> 6, acc, wave, lane, As0, Bs0, As1, Bs1);
    #pragma unroll
    for (int i = 0; i < 4; ++i){
        #pragma unroll
        for (int r = 0; r < 4; ++r){
            const int m = m0 + wm + i*16 + quad*4 + r;
            const float bm = BIAS_M ? bias[m] : 0.f;
            #pragma unroll
            for (int j = 0; j < 4; ++j){
                const int n = n0 + wn + j*16 + l15;
                float v = acc[i][j][r] + (BIAS_M ? bm : bias[n]);
                if constexpr (RELU) v = fmaxf(v, 0.f);
                if constexpr (RES) v += resF[(size_t)m*N + n];
                if constexpr (OUTF) outF[(size_t)m*N + n] = v;
                else outB[(size_t)m*N + n] = f2bfbits(v);
            }
        }
    }
}

// generic single GEMM (double-buffered)
template<bool RELU, bool RES, bool OUTF, bool BIAS_M>
__global__ __launch_bounds__(256)
void gemm_mfma(const unsigned short* __restrict__ A, const unsigned short* __restrict__ B,
               const float* __restrict__ bias, const float* __restrict__ resF,
               unsigned short* __restrict__ outB, float* __restrict__ outF,
               const int N, const int K, const int lda, const int ldb)
{
    DECL_DB
    const int3 b = xcd_swz();
    gemm_core<RELU,RES,OUTF,BIAS_M>(A, B, bias, resF, outB, outF, N, K, lda, ldb,
                                    b.y*128, b.x*128, As0, Bs0, As1, Bs1);
}

// ---------- fused Q/K/VT projections: 1536 uniform tiles in ONE launch ----------
// db core + reordered VT ids (m0 fastest): the untested cell of the
// {buffering x VT-order} 2x2. New order minimizes miss volume (FETCH 99->49MB,
// R9); db hides the residual L2/stream latency (as it did for dense, R8).
__global__ __launch_bounds__(256)
void proj_fused(const unsigned short* __restrict__ LN,
                const unsigned short* __restrict__ WqT, const unsigned short* __restrict__ WkT,
                const unsigned short* __restrict__ WvT,
                const float* __restrict__ bq, const float* __restrict__ bk,
                const float* __restrict__ bv,
                unsigned short* __restrict__ Qw, unsigned short* __restrict__ Kw,
                unsigned short* __restrict__ VTw)
{
    DECL_DB
    const int lin = blockIdx.x;                    // 1536
    const int id = (lin & 7) * 192 + (lin >> 3);   // chunked XCD swizzle
    if (id < 1024){
        const bool isK = (id >= 512);
        const int q = id & 511;
        const int n0 = (q & 7) * 128, m0 = (q >> 3) * 128;   // n over DD, m over MM
        gemm_core<false,false,false,false>(LN, isK ? WkT : WqT, isK ? bk : bq, nullptr,
                                           isK ? Kw : Qw, nullptr, DD, DD, DD, DD,
                                           m0, n0, As0, Bs0, As1, Bs1);
    } else {
        const int q = id - 1024;
        const int m0 = (q & 7) * 128, n0 = (q >> 3) * 128;   // m over DD, n over MM
        gemm_core<false,false,false,true>(WvT, LN, bv, nullptr, VTw, nullptr,
                                          MM, DD, DD, DD, m0, n0, As0, Bs0, As1, Bs1);
    }
}

// ---------- scores: packed P = exp(Q*K^T * scale), causal, UNNORMALIZED ----------
__global__ __launch_bounds__(256)
void scores_mfma(const unsigned short* __restrict__ Qb, const unsigned short* __restrict__ Kb,
                 unsigned short* __restrict__ Pb, float* __restrict__ Lf, const float scale)
{
    const int lin = blockIdx.x;                    // 544 = 4 * 136
    const int id = (lin & 7) * 68 + (lin >> 3);    // chunked XCD swizzle
    const int z = id / 136;
    const int idx = id - z * 136;
    int y = (int)((sqrtf(8.f * (float)idx + 1.f) - 1.f) * 0.5f);
    while ((y + 1) * (y + 2) / 2 <= idx) ++y;      // guard float error
    while (y * (y + 1) / 2 > idx) --y;
    const int x = idx - y * (y + 1) / 2;           // x <= y
    const int s0 = y * 128, t0 = x * 128;

    const unsigned short* Q  = Qb + (size_t)z*SD;
    const unsigned short* Km = Kb + (size_t)z*SD;
    unsigned short* P        = Pb + (size_t)z*PPB;
    float* L                 = Lf + (size_t)z*SS;
    DECL_DB
    const int tid = threadIdx.x, lane = tid & 63, wave = tid >> 6;
    const int wm = ((wave >> 1) & 1) * 64, wn = (wave & 1) * 64;
    const int quad = lane >> 4, l15 = lane & 15;
    const unsigned short* ga[4]; const unsigned short* gb[4];
    mk_chunks(Q,  DD, s0, wave, lane, ga);
    mk_chunks(Km, DD, t0, wave, lane, gb);
    f32x4 acc[4][4] = {};
    mfma_db<false>(ga, gb, nullptr, nullptr, DD >> 6, acc, wave, lane, As0, Bs0, As1, Bs1);

    #pragma unroll
    for (int i = 0; i < 4; ++i){
        #pragma unroll
        for (int r = 0; r < 4; ++r){
            const int s = s0 + wm + i*16 + quad*4 + r;
            const int width = rowWidth(s);
            unsigned short* pr = P + rowOff(s);
            float psum = 0.f;
            if (t0 + wn < width){                    // 64-chunk uniform in/out
                #pragma unroll
                for (int j = 0; j < 4; ++j){
                    const int t = t0 + wn + j*16 + l15;
                    const float e = (t <= s) ? __expf(acc[i][j][r] * scale) : 0.f;
                    pr[t] = f2bfbits(e);
                    psum += e;
                }
                #pragma unroll
                for (int off = 8; off > 0; off >>= 1) psum += __shfl_xor(psum, off, 64);
                if (l15 == 0) atomicAdd(&L[s], psum);
            }
        }
    }
}

// ---------- ctx = (P @ V) / l ; A=packed unnormalized P, B=VT[d][tok] ----------
// Causal-balance remap: y' = (z>=2) ? 15-y : y (complementary co-resident pairs).
__global__ __launch_bounds__(256)
void pv_mfma(const unsigned short* __restrict__ Pb, const unsigned short* __restrict__ VT,
             unsigned short* __restrict__ Cb, const unsigned short* __restrict__ zpad,
             const float* __restrict__ Lf)
{
    const int yr = blockIdx.y;
    const int y  = (blockIdx.z >= 2) ? (15 - yr) : yr;
    const int s0 = y*128, n0 = blockIdx.x*128;
    const unsigned short* P = Pb + (size_t)blockIdx.z*PPB;
    unsigned short* C       = Cb + (size_t)blockIdx.z*SD;
    const float* L          = Lf + (size_t)blockIdx.z*SS;
    const int bcol = blockIdx.z*SS;
    DECL_DB
    const int tid = threadIdx.x, lane = tid & 63, wave = tid >> 6;
    const int wm = ((wave >> 1) & 1) * 64, wn = (wave & 1) * 64;
    const int quad = lane >> 4, l15 = lane & 15;
    const unsigned short* ga[4]; const unsigned short* gb[4]; int pw[4];
    #pragma unroll
    for (int c = 0; c < 4; ++c){
        const int mr = (wave*4 + c)*8 + (lane >> 3);
        const int gk = ((lane & 7) - mr) & 7;
        const int s = s0 + mr;
        pw[c] = rowWidth(s) - gk*8;                 // chunk valid iff koff < pw
        ga[c] = P + rowOff(s) + gk*8;
    }
    mk_chunks(VT + bcol, MM, n0, wave, lane, gb);
    f32x4 acc[4][4] = {};
    const int NT = (s0 >> 6) + 2;                   // 2y+2, even
    mfma_db<true>(ga, gb, pw, zpad, NT, acc, wave, lane, As0, Bs0, As1, Bs1);

    #pragma unroll
    for (int i = 0; i < 4; ++i){
        #pragma unroll
        for (int r = 0; r < 4; ++r){
            const int s = s0 + wm + i*16 + quad*4 + r;
            const float linv = 1.0f / L[s];
            #pragma unroll
            for (int j = 0; j < 4; ++j){
                const int n = n0 + wn + j*16 + l15;
                C[(size_t)s*DD + n] = f2bfbits(acc[i][j][r] * linv);
            }
        }
    }
}

extern "C" void kernel_launch(void* const* d_in, const int* in_sizes, int n_in,
                              void* d_out, int out_size, void* d_ws, size_t ws_size,
                              hipStream_t stream)
{
    (void)in_sizes; (void)n_in; (void)out_size;
    const float* x   = (const float*)d_in[0];
    const float* bq  = (const float*)d_in[2];
    const float* bk  = (const float*)d_in[4];
    const float* bv  = (const float*)d_in[6];
    const float* bo  = (const float*)d_in[8];
    const float* b1  = (const float*)d_in[10];
    const float* b2  = (const float*)d_in[12];
    const float* g1  = (const float*)d_in[13];
    const float* be1 = (const float*)d_in[14];
    const float* g2  = (const float*)d_in[15];
    const float* be2 = (const float*)d_in[16];
    float* outf = (float*)d_out;

    if (ws_size < (size_t)REQ_WS){
        sentinel_kernel<<<dim3((unsigned)(MD/256)), dim3(256), 0, stream>>>(outf, 1.0e9f);
        return;
    }

    unsigned short* wsb = (unsigned short*)d_ws;
    unsigned short* Qw  = wsb;                 // -> ctx
    unsigned short* Kw  = wsb + MD;            // \ -> Hf (fp32 spans K+VT)
    unsigned short* VTw = wsb + 2*MD;          // /
    unsigned short* Pw  = wsb + 3*MD;          // packed P -> mid
    unsigned short* WT  = wsb + WT_OFF;
    unsigned short* ZP  = wsb + ZP_OFF;
    float*          Lf  = (float*)(wsb + LF_OFF);
    float*          Hf  = (float*)Kw;
    unsigned short* CTX = Qw;
    unsigned short* MIDw= Pw;
    unsigned short* LN  = (unsigned short*)d_out;   // LN1/LN2 scratch in d_out

    PrepArgs pa;
    static const int widx[6] = {1,3,5,7,9,11};
    for (int i = 0; i < 6; ++i){
        pa.wp.w[i] = (const float*)d_in[widx[i]];
        pa.wp.o[i] = WT + (size_t)i*DD*DD;
    }
    pa.wp.zp = ZP;
    pa.wp.lf = Lf;
    pa.x = x; pa.g1 = g1; pa.be1 = be1; pa.ln = LN;
    unsigned short* WqT = pa.wp.o[0]; unsigned short* WkT = pa.wp.o[1];
    unsigned short* WvT = pa.wp.o[2]; unsigned short* WoT = pa.wp.o[3];
    unsigned short* W1T = pa.wp.o[4]; unsigned short* W2T = pa.wp.o[5];

    const dim3 blk(256);
    const float scale = 1.0f / sqrtf((float)SS);
    const dim3 gA(DD/128, MM/128);    // (8,64)

    // fused wtrans + LN1 (independent streams, one launch)
    prep<<<dim3(1536 + MM), blk, 0, stream>>>(pa);
    // fused Q + K + VT projections (1536 uniform tiles, one launch)
    proj_fused<<<dim3(1536), blk, 0, stream>>>(LN, WqT, WkT, WvT, bq, bk, bv, Qw, Kw, VTw);
    // attention: fused exp-scores (+row sums, triangular-packed) then PV (/rowsum)
    scores_mfma<<<dim3(544), blk, 0, stream>>>(Qw, Kw, Pw, Lf, scale);
    pv_mfma<<<dim3(DD/128, SS/128, BB), blk, 0, stream>>>(Pw, VTw, CTX, ZP, Lf);
    // h = ctx*WoT^T + bo + x (fp32)
    gemm_mfma<false,true,true,false><<<gA, blk, 0, stream>>>(CTX, WoT, bo, x, nullptr, Hf, DD, DD, DD, DD);
    ln_f32<<<dim3(MM), blk, 0, stream>>>(Hf, g2, be2, LN);
    // mid = relu(LN*W1T^T + b1)
    gemm_mfma<true,false,false,false><<<gA, blk, 0, stream>>>(LN, W1T, b1, nullptr, MIDw, nullptr, DD, DD, DD, DD);
    // out = mid*W2T^T + b2 + h
    gemm_mfma<false,true,true,false><<<gA, blk, 0, stream>>>(MIDw, W2T, b2, Hf, nullptr, outf, DD, DD, DD, DD);
}